// Round 1
// baseline (991.384 us; speedup 1.0000x reference)
//
#include <hip/hip_runtime.h>
#include <math.h>

#define NODES 50000
#define NEDGE 400000
#define ETOT  450000   // NEDGE + NODES self loops
#define DIN   256
#define C1    256      // heads*dh = 8*32
#define C2    40

static __device__ __forceinline__ float lrelu(float v) { return v > 0.f ? v : 0.2f * v; }

// ---------------- CSR build ----------------
__global__ void zero_int(int* p, int n) {
    int i = blockIdx.x * blockDim.x + threadIdx.x;
    if (i < n) p[i] = 0;
}

__global__ void count_kernel(const int* __restrict__ dstRow, int* __restrict__ cnt) {
    int e = blockIdx.x * blockDim.x + threadIdx.x;
    if (e >= ETOT) return;
    int d = (e < NEDGE) ? dstRow[e] : (e - NEDGE);
    atomicAdd(&cnt[d], 1);
}

__global__ void scan_kernel(const int* __restrict__ cnt, int* __restrict__ off, int n) {
    __shared__ int buf[1024];
    __shared__ int carry;
    int t = threadIdx.x;
    if (t == 0) carry = 0;
    __syncthreads();
    for (int base = 0; base < n; base += 1024) {
        int i = base + t;
        int v = (i < n) ? cnt[i] : 0;
        buf[t] = v;
        __syncthreads();
        for (int d = 1; d < 1024; d <<= 1) {
            int add = (t >= d) ? buf[t - d] : 0;
            __syncthreads();
            buf[t] += add;
            __syncthreads();
        }
        int incl = buf[t];
        int excl = incl - v;
        if (i < n) off[i] = carry + excl;
        __syncthreads();
        if (t == 1023) carry += incl;
        __syncthreads();
    }
    if (t == 0) off[n] = carry;
}

__global__ void place_kernel(const int* __restrict__ dstRow, const int* __restrict__ off,
                             int* __restrict__ cnt, int* __restrict__ csr) {
    int e = blockIdx.x * blockDim.x + threadIdx.x;
    if (e >= ETOT) return;
    int d = (e < NEDGE) ? dstRow[e] : (e - NEDGE);
    int slot = off[d] + atomicAdd(&cnt[d], 1);
    csr[slot] = e;
}

// ---------------- dual GEMM: Cl = A@Bl + bl, Cr = A@Br + br ----------------
#define BM 64
#define BN 64
#define BK 16

__global__ __launch_bounds__(256)
void dual_gemm(const float* __restrict__ A,
               const float* __restrict__ Bl, const float* __restrict__ Br,
               const float* __restrict__ bl, const float* __restrict__ br,
               float* __restrict__ Cl, float* __restrict__ Cr,
               int M, int K, int Nout)
{
    __shared__ float As[BM][BK + 1];
    __shared__ float Bsl[BK][BN + 1];
    __shared__ float Bsr[BK][BN + 1];

    const int tid = threadIdx.x;
    const int row0 = blockIdx.x * BM;
    const int col0 = blockIdx.y * BN;
    const int ty = tid >> 4;         // 0..15
    const int tx = tid & 15;         // 0..15

    const int ar = tid >> 2;          // 0..63
    const int ac = (tid & 3) << 2;    // 0,4,8,12
    const int brow = tid >> 4;        // 0..15
    const int bcol = (tid & 15) << 2; // 0..60

    float accl[4][4] = {};
    float accr[4][4] = {};

    for (int k0 = 0; k0 < K; k0 += BK) {
        // A tile (64 x 16)
        {
            int r = row0 + ar;
            if (r < M) {
                const float4 v = *(const float4*)(A + (size_t)r * K + k0 + ac);
                As[ar][ac + 0] = v.x; As[ar][ac + 1] = v.y;
                As[ar][ac + 2] = v.z; As[ar][ac + 3] = v.w;
            } else {
                As[ar][ac + 0] = 0.f; As[ar][ac + 1] = 0.f;
                As[ar][ac + 2] = 0.f; As[ar][ac + 3] = 0.f;
            }
        }
        // B tiles (16 x 64), guarded scalar loads
        #pragma unroll
        for (int j = 0; j < 4; ++j) {
            int c = col0 + bcol + j;
            float vl = 0.f, vr = 0.f;
            if (c < Nout) {
                vl = Bl[(size_t)(k0 + brow) * Nout + c];
                vr = Br[(size_t)(k0 + brow) * Nout + c];
            }
            Bsl[brow][bcol + j] = vl;
            Bsr[brow][bcol + j] = vr;
        }
        __syncthreads();
        #pragma unroll
        for (int kk = 0; kk < BK; ++kk) {
            float a[4], pl[4], pr[4];
            #pragma unroll
            for (int i = 0; i < 4; ++i) a[i] = As[ty * 4 + i][kk];
            #pragma unroll
            for (int j = 0; j < 4; ++j) { pl[j] = Bsl[kk][tx * 4 + j]; pr[j] = Bsr[kk][tx * 4 + j]; }
            #pragma unroll
            for (int i = 0; i < 4; ++i)
                #pragma unroll
                for (int j = 0; j < 4; ++j) {
                    accl[i][j] += a[i] * pl[j];
                    accr[i][j] += a[i] * pr[j];
                }
        }
        __syncthreads();
    }

    #pragma unroll
    for (int i = 0; i < 4; ++i) {
        int r = row0 + ty * 4 + i;
        if (r >= M) continue;
        #pragma unroll
        for (int j = 0; j < 4; ++j) {
            int c = col0 + tx * 4 + j;
            if (c >= Nout) continue;
            Cl[(size_t)r * Nout + c] = accl[i][j] + bl[c];
            Cr[(size_t)r * Nout + c] = accr[i][j] + br[c];
        }
    }
}

// ---------------- layer 1 edge logits: one wave per edge ----------------
__global__ __launch_bounds__(256)
void edge_logits1(const int* __restrict__ ei, const float* __restrict__ xl,
                  const float* __restrict__ xr, const float* __restrict__ att,
                  float* __restrict__ s1)
{
    int e = ((blockIdx.x * blockDim.x + threadIdx.x) >> 6);
    int lane = threadIdx.x & 63;
    if (e >= ETOT) return;
    int src, dst;
    if (e < NEDGE) { src = ei[e]; dst = ei[NEDGE + e]; }
    else           { src = e - NEDGE; dst = src; }
    int c0 = lane * 4;
    const float4 a = *(const float4*)(xl + (size_t)src * C1 + c0);
    const float4 b = *(const float4*)(xr + (size_t)dst * C1 + c0);
    const float4 w = *(const float4*)(att + c0);
    float p = lrelu(a.x + b.x) * w.x + lrelu(a.y + b.y) * w.y
            + lrelu(a.z + b.z) * w.z + lrelu(a.w + b.w) * w.w;
    p += __shfl_xor(p, 1);
    p += __shfl_xor(p, 2);
    p += __shfl_xor(p, 4);
    if ((lane & 7) == 0) s1[(size_t)e * 8 + (lane >> 3)] = p;
}

// ---------------- layer 1 softmax over in-edges (alpha in place) ----------------
__global__ void softmax1(const int* __restrict__ off, const int* __restrict__ csr,
                         float* __restrict__ s1)
{
    int n = blockIdx.x * blockDim.x + threadIdx.x;
    if (n >= NODES) return;
    int a = off[n], b = off[n + 1];
    float m[8];
    #pragma unroll
    for (int h = 0; h < 8; ++h) m[h] = -INFINITY;
    for (int i = a; i < b; ++i) {
        int e = csr[i];
        #pragma unroll
        for (int h = 0; h < 8; ++h) m[h] = fmaxf(m[h], s1[(size_t)e * 8 + h]);
    }
    float d[8] = {0.f, 0.f, 0.f, 0.f, 0.f, 0.f, 0.f, 0.f};
    for (int i = a; i < b; ++i) {
        int e = csr[i];
        #pragma unroll
        for (int h = 0; h < 8; ++h) {
            float ex = expf(s1[(size_t)e * 8 + h] - m[h]);
            s1[(size_t)e * 8 + h] = ex;
            d[h] += ex;
        }
    }
    #pragma unroll
    for (int h = 0; h < 8; ++h) d[h] = 1.f / d[h];
    for (int i = a; i < b; ++i) {
        int e = csr[i];
        #pragma unroll
        for (int h = 0; h < 8; ++h) s1[(size_t)e * 8 + h] *= d[h];
    }
}

// ---------------- layer 1 aggregation + bias + ELU ----------------
__global__ __launch_bounds__(256)
void aggregate1(const int* __restrict__ ei, const int* __restrict__ off,
                const int* __restrict__ csr, const float* __restrict__ s1,
                const float* __restrict__ xl, const float* __restrict__ bias,
                float* __restrict__ hout)
{
    int n = blockIdx.x;
    int c = threadIdx.x;
    int hh = c >> 5;
    float acc = 0.f;
    int a = off[n], b = off[n + 1];
    for (int i = a; i < b; ++i) {
        int e = csr[i];
        int src = (e < NEDGE) ? ei[e] : (e - NEDGE);
        float alpha = s1[(size_t)e * 8 + hh];
        acc += alpha * xl[(size_t)src * C1 + c];
    }
    float v = acc + bias[c];
    hout[(size_t)n * C1 + c] = v > 0.f ? v : (expf(v) - 1.f);
}

// ---------------- layer 2 edge logits: one wave per edge ----------------
__global__ __launch_bounds__(256)
void edge_logits2(const int* __restrict__ ei, const float* __restrict__ h2l,
                  const float* __restrict__ h2r, const float* __restrict__ att,
                  float* __restrict__ s2)
{
    int e = ((blockIdx.x * blockDim.x + threadIdx.x) >> 6);
    int lane = threadIdx.x & 63;
    if (e >= ETOT) return;
    int src, dst;
    if (e < NEDGE) { src = ei[e]; dst = ei[NEDGE + e]; }
    else           { src = e - NEDGE; dst = src; }
    float p = 0.f;
    if (lane < C2) {
        float v = h2l[(size_t)src * C2 + lane] + h2r[(size_t)dst * C2 + lane];
        p = lrelu(v) * att[lane];
    }
    #pragma unroll
    for (int o = 32; o > 0; o >>= 1) p += __shfl_xor(p, o);
    if (lane == 0) s2[e] = p;
}

// ---------------- layer 2 softmax (alpha in place) ----------------
__global__ void softmax2(const int* __restrict__ off, const int* __restrict__ csr,
                         float* __restrict__ s2)
{
    int n = blockIdx.x * blockDim.x + threadIdx.x;
    if (n >= NODES) return;
    int a = off[n], b = off[n + 1];
    float m = -INFINITY;
    for (int i = a; i < b; ++i) m = fmaxf(m, s2[csr[i]]);
    float d = 0.f;
    for (int i = a; i < b; ++i) {
        float ex = expf(s2[csr[i]] - m);
        s2[csr[i]] = ex;
        d += ex;
    }
    float inv = 1.f / d;
    for (int i = a; i < b; ++i) s2[csr[i]] *= inv;
}

// ---------------- layer 2 aggregation + bias + log_softmax ----------------
__global__ __launch_bounds__(64)
void aggregate2(const int* __restrict__ ei, const int* __restrict__ off,
                const int* __restrict__ csr, const float* __restrict__ s2,
                const float* __restrict__ h2l, const float* __restrict__ bias,
                float* __restrict__ out)
{
    int n = blockIdx.x;
    int c = threadIdx.x;   // 0..63, active 0..39
    float acc = 0.f;
    int a = off[n], b = off[n + 1];
    for (int i = a; i < b; ++i) {
        int e = csr[i];
        int src = (e < NEDGE) ? ei[e] : (e - NEDGE);
        float alpha = s2[e];
        if (c < C2) acc += alpha * h2l[(size_t)src * C2 + c];
    }
    float v = (c < C2) ? (acc + bias[c]) : -INFINITY;
    float mx = v;
    #pragma unroll
    for (int o = 32; o > 0; o >>= 1) mx = fmaxf(mx, __shfl_xor(mx, o));
    float ex = (c < C2) ? expf(v - mx) : 0.f;
    float s = ex;
    #pragma unroll
    for (int o = 32; o > 0; o >>= 1) s += __shfl_xor(s, o);
    if (c < C2) out[(size_t)n * C2 + c] = v - mx - logf(s);
}

extern "C" void kernel_launch(void* const* d_in, const int* in_sizes, int n_in,
                              void* d_out, int out_size, void* d_ws, size_t ws_size,
                              hipStream_t stream)
{
    const float* x     = (const float*)d_in[0];
    const int*   ei    = (const int*)  d_in[1];
    const float* W1l   = (const float*)d_in[2];
    const float* b1l   = (const float*)d_in[3];
    const float* W1r   = (const float*)d_in[4];
    const float* b1r   = (const float*)d_in[5];
    const float* att1  = (const float*)d_in[6];
    const float* bias1 = (const float*)d_in[7];
    const float* W2l   = (const float*)d_in[8];
    const float* b2l   = (const float*)d_in[9];
    const float* W2r   = (const float*)d_in[10];
    const float* b2r   = (const float*)d_in[11];
    const float* att2  = (const float*)d_in[12];
    const float* bias2 = (const float*)d_in[13];
    float* out = (float*)d_out;

    float* ws  = (float*)d_ws;
    float* xl1 = ws;                      // NODES*256 = 12.8M floats
    float* xr1 = ws + 12800000;           // NODES*256 (reused as h)
    float* s1  = ws + 25600000;           // ETOT*8 = 3.6M floats
    int*   csr = (int*)(ws + 29200000);   // ETOT ints
    int*   off = csr + ETOT;              // NODES+1
    int*   cnt = off + (NODES + 1);       // NODES
    float* h   = xr1;
    float* h2l = xl1;                     // NODES*40 = 2.0M floats
    float* h2r = xl1 + (size_t)NODES * C2;
    float* s2  = xl1 + (size_t)2 * NODES * C2;

    const int* dstRow = ei + NEDGE;

    // ---- CSR build (counting sort over dst) ----
    zero_int<<<(NODES + 255) / 256, 256, 0, stream>>>(cnt, NODES);
    count_kernel<<<(ETOT + 255) / 256, 256, 0, stream>>>(dstRow, cnt);
    scan_kernel<<<1, 1024, 0, stream>>>(cnt, off, NODES);
    zero_int<<<(NODES + 255) / 256, 256, 0, stream>>>(cnt, NODES);
    place_kernel<<<(ETOT + 255) / 256, 256, 0, stream>>>(dstRow, off, cnt, csr);

    // ---- layer 1 ----
    {
        dim3 g((NODES + BM - 1) / BM, C1 / BN);
        dual_gemm<<<g, 256, 0, stream>>>(x, W1l, W1r, b1l, b1r, xl1, xr1, NODES, DIN, C1);
    }
    edge_logits1<<<(ETOT + 3) / 4, 256, 0, stream>>>(ei, xl1, xr1, att1, s1);
    softmax1<<<(NODES + 255) / 256, 256, 0, stream>>>(off, csr, s1);
    aggregate1<<<NODES, 256, 0, stream>>>(ei, off, csr, s1, xl1, bias1, h);

    // ---- layer 2 ----
    {
        dim3 g((NODES + BM - 1) / BM, 1);
        dual_gemm<<<g, 256, 0, stream>>>(h, W2l, W2r, b2l, b2r, h2l, h2r, NODES, C1, C2);
    }
    edge_logits2<<<(ETOT + 3) / 4, 256, 0, stream>>>(ei, h2l, h2r, att2, s2);
    softmax2<<<(NODES + 255) / 256, 256, 0, stream>>>(off, csr, s2);
    aggregate2<<<NODES, 64, 0, stream>>>(ei, off, csr, s2, h2l, bias2, out);
}

// Round 2
// 687.323 us; speedup vs baseline: 1.4424x; 1.4424x over previous
//
#include <hip/hip_runtime.h>
#include <math.h>

#define NODES 50000
#define NEDGE 400000
#define ETOT  450000   // NEDGE + NODES self loops
#define DIN   256
#define C1    256      // heads*dh = 8*32
#define C2    40

typedef __attribute__((ext_vector_type(8))) short bfrag;
typedef __attribute__((ext_vector_type(4))) float facc;

#define GPTR(p) (const __attribute__((address_space(1))) unsigned int*)(p)
#define LPTR(p) (__attribute__((address_space(3))) unsigned int*)(p)

static __device__ __forceinline__ float lrelu(float v) { return v > 0.f ? v : 0.2f * v; }

static __device__ __forceinline__ float bf2f(unsigned int u16) {
    unsigned int x = u16 << 16;
    float f;
    __builtin_memcpy(&f, &x, 4);
    return f;
}
static __device__ __forceinline__ unsigned short f2bf(float f) {
    unsigned int x;
    __builtin_memcpy(&x, &f, 4);
    unsigned int r = x + 0x7fffu + ((x >> 16) & 1u);   // RNE
    return (unsigned short)(r >> 16);
}

// ---------------- CSR build ----------------
__global__ void zero_int(int* p, int n) {
    int i = blockIdx.x * blockDim.x + threadIdx.x;
    if (i < n) p[i] = 0;
}

__global__ void count_kernel(const int* __restrict__ dstRow, int* __restrict__ cnt) {
    int e = blockIdx.x * blockDim.x + threadIdx.x;
    if (e >= ETOT) return;
    int d = (e < NEDGE) ? dstRow[e] : (e - NEDGE);
    atomicAdd(&cnt[d], 1);
}

__global__ void scan_kernel(const int* __restrict__ cnt, int* __restrict__ off, int n) {
    __shared__ int buf[1024];
    __shared__ int carry;
    int t = threadIdx.x;
    if (t == 0) carry = 0;
    __syncthreads();
    for (int base = 0; base < n; base += 1024) {
        int i = base + t;
        int v = (i < n) ? cnt[i] : 0;
        buf[t] = v;
        __syncthreads();
        for (int d = 1; d < 1024; d <<= 1) {
            int add = (t >= d) ? buf[t - d] : 0;
            __syncthreads();
            buf[t] += add;
            __syncthreads();
        }
        int incl = buf[t];
        int excl = incl - v;
        if (i < n) off[i] = carry + excl;
        __syncthreads();
        if (t == 1023) carry += incl;
        __syncthreads();
    }
    if (t == 0) off[n] = carry;
}

__global__ void place_kernel(const int* __restrict__ dstRow, const int* __restrict__ off,
                             int* __restrict__ cnt, int* __restrict__ csr) {
    int e = blockIdx.x * blockDim.x + threadIdx.x;
    if (e >= ETOT) return;
    int d = (e < NEDGE) ? dstRow[e] : (e - NEDGE);
    int slot = off[d] + atomicAdd(&cnt[d], 1);
    csr[slot] = e;
}

// ---------------- weight transpose+cast: Wt[n][k] = bf16(W[k][n]) ----------------
__global__ void prep_w(const float* __restrict__ Wl, const float* __restrict__ Wr,
                       unsigned short* __restrict__ Wt, int K, int Nhalf) {
    int idx = blockIdx.x * 256 + threadIdx.x;   // n*K + k
    int n = idx / K;
    int k = idx - n * K;
    if (n >= 2 * Nhalf) return;
    float v = (n < Nhalf) ? Wl[(size_t)k * Nhalf + n] : Wr[(size_t)k * Nhalf + (n - Nhalf)];
    Wt[idx] = f2bf(v);
}

// ---------------- MFMA dual GEMM ----------------
// C[:, :Nhalf] -> Cl (+bl), C[:, Nhalf:2*Nhalf] -> Cr (+br)
// A: [M][K] (f32 if !ABF16 else bf16), Bt: [Nrows][K] bf16 (rows of Bt = cols of C)
#define GBM 128
#define GBN 128
#define GBK 32

template<bool ABF16, typename OUTT>
__global__ __launch_bounds__(256)
void mfma_gemm(const void* __restrict__ Av, const unsigned short* __restrict__ Bt,
               const float* __restrict__ bl, const float* __restrict__ br,
               OUTT* __restrict__ Cl, OUTT* __restrict__ Cr,
               int M, int K, int Nrows, int Nhalf)
{
    __shared__ __align__(16) unsigned short As[GBM * GBK];
    __shared__ __align__(16) unsigned short Bs[GBN * GBK];

    const int tid  = threadIdx.x;
    const int lane = tid & 63;
    const int w    = tid >> 6;       // wave 0..3
    const int wr   = w >> 1;
    const int wc   = w & 1;
    const int row0 = blockIdx.x * GBM;
    const int col0 = blockIdx.y * GBN;

    facc acc[4][4];
    #pragma unroll
    for (int i = 0; i < 4; ++i)
        #pragma unroll
        for (int j = 0; j < 4; ++j) {
            facc z = {0.f, 0.f, 0.f, 0.f};
            acc[i][j] = z;
        }

    // staging lane mapping for global_load_lds chunks (1 KiB per wave-instruction)
    const int rA  = lane >> 2;            // row within 16-row chunk
    const int sA  = lane & 3;             // 16B slot within 64B row
    const int kgA = sA ^ ((rA >> 1) & 3); // pre-swizzled source k-group

    for (int k0 = 0; k0 < K; k0 += GBK) {
        if (k0) __syncthreads();

        // ---- stage A ----
        if constexpr (ABF16) {
            const unsigned short* Ab = (const unsigned short*)Av;
            #pragma unroll
            for (int p = 0; p < 2; ++p) {
                int chunk = p * 4 + w;
                int r_loc = chunk * 16 + rA;
                int grow  = row0 + r_loc;
                if (grow < M)
                    __builtin_amdgcn_global_load_lds(
                        GPTR(Ab + (size_t)grow * K + k0 + kgA * 8),
                        LPTR(As + chunk * 512), 16, 0, 0);
            }
        } else {
            const float* Af = (const float*)Av;
            #pragma unroll
            for (int p = 0; p < 2; ++p) {
                int r_loc = p * 64 + (tid >> 2);
                int g     = tid & 3;
                int grow  = row0 + r_loc;
                float v[8];
                if (grow < M) {
                    const float4* ap = (const float4*)(Af + (size_t)grow * K + k0 + g * 8);
                    float4 u0 = ap[0], u1 = ap[1];
                    v[0] = u0.x; v[1] = u0.y; v[2] = u0.z; v[3] = u0.w;
                    v[4] = u1.x; v[5] = u1.y; v[6] = u1.z; v[7] = u1.w;
                } else {
                    #pragma unroll
                    for (int j = 0; j < 8; ++j) v[j] = 0.f;
                }
                int slot = g ^ ((r_loc >> 1) & 3);
                bfrag pk;
                #pragma unroll
                for (int j = 0; j < 8; ++j) pk[j] = (short)f2bf(v[j]);
                *(bfrag*)(As + r_loc * 32 + slot * 8) = pk;
            }
        }

        // ---- stage B ----
        #pragma unroll
        for (int p = 0; p < 2; ++p) {
            int chunk = p * 4 + w;
            int r_loc = chunk * 16 + rA;
            int grow  = col0 + r_loc;
            if (grow < Nrows)
                __builtin_amdgcn_global_load_lds(
                    GPTR(Bt + (size_t)grow * K + k0 + kgA * 8),
                    LPTR(Bs + chunk * 512), 16, 0, 0);
        }

        __syncthreads();

        // ---- fragments + MFMA ----
        const int fr    = lane & 15;
        const int sRead = (lane >> 4) ^ ((fr >> 1) & 3);
        bfrag af[4], bfv[4];
        #pragma unroll
        for (int mi = 0; mi < 4; ++mi)
            af[mi] = *(const bfrag*)(As + (wr * 64 + mi * 16 + fr) * 32 + sRead * 8);
        #pragma unroll
        for (int ni = 0; ni < 4; ++ni)
            bfv[ni] = *(const bfrag*)(Bs + (wc * 64 + ni * 16 + fr) * 32 + sRead * 8);
        #pragma unroll
        for (int mi = 0; mi < 4; ++mi)
            #pragma unroll
            for (int ni = 0; ni < 4; ++ni)
                acc[mi][ni] = __builtin_amdgcn_mfma_f32_16x16x32_bf16(
                    af[mi], bfv[ni], acc[mi][ni], 0, 0, 0);
    }

    // ---- epilogue: C/D layout col=lane&15, row=(lane>>4)*4+reg ----
    #pragma unroll
    for (int mi = 0; mi < 4; ++mi) {
        const int rbase = row0 + wr * 64 + mi * 16 + ((lane >> 4) << 2);
        #pragma unroll
        for (int ni = 0; ni < 4; ++ni) {
            const int col = col0 + wc * 64 + ni * 16 + (lane & 15);
            #pragma unroll
            for (int rg = 0; rg < 4; ++rg) {
                int r = rbase + rg;
                if (r >= M) continue;
                float v = acc[mi][ni][rg];
                if (col < Nhalf) {
                    v += bl[col];
                    if constexpr (sizeof(OUTT) == 2)
                        Cl[(size_t)r * Nhalf + col] = (OUTT)f2bf(v);
                    else
                        Cl[(size_t)r * Nhalf + col] = (OUTT)v;
                } else if (col < 2 * Nhalf) {
                    int c2 = col - Nhalf;
                    v += br[c2];
                    if constexpr (sizeof(OUTT) == 2)
                        Cr[(size_t)r * Nhalf + c2] = (OUTT)f2bf(v);
                    else
                        Cr[(size_t)r * Nhalf + c2] = (OUTT)v;
                }
            }
        }
    }
}

// ---------------- layer 1 edge logits: one wave per edge (bf16 xl/xr) ----------------
__global__ __launch_bounds__(256)
void edge_logits1(const int* __restrict__ ei, const unsigned short* __restrict__ xl,
                  const unsigned short* __restrict__ xr, const float* __restrict__ att,
                  float* __restrict__ s1)
{
    int e = ((blockIdx.x * blockDim.x + threadIdx.x) >> 6);
    int lane = threadIdx.x & 63;
    if (e >= ETOT) return;
    int src, dst;
    if (e < NEDGE) { src = ei[e]; dst = ei[NEDGE + e]; }
    else           { src = e - NEDGE; dst = src; }
    int c0 = lane * 4;
    uint2 ua = *(const uint2*)(xl + (size_t)src * C1 + c0);
    uint2 ub = *(const uint2*)(xr + (size_t)dst * C1 + c0);
    float4 wv = *(const float4*)(att + c0);
    float a0 = bf2f(ua.x & 0xffff), a1 = bf2f(ua.x >> 16);
    float a2 = bf2f(ua.y & 0xffff), a3 = bf2f(ua.y >> 16);
    float b0 = bf2f(ub.x & 0xffff), b1 = bf2f(ub.x >> 16);
    float b2 = bf2f(ub.y & 0xffff), b3 = bf2f(ub.y >> 16);
    float p = lrelu(a0 + b0) * wv.x + lrelu(a1 + b1) * wv.y
            + lrelu(a2 + b2) * wv.z + lrelu(a3 + b3) * wv.w;
    p += __shfl_xor(p, 1);
    p += __shfl_xor(p, 2);
    p += __shfl_xor(p, 4);
    if ((lane & 7) == 0) s1[(size_t)e * 8 + (lane >> 3)] = p;
}

// ---------------- layer 1 softmax over in-edges (alpha in place) ----------------
__global__ void softmax1(const int* __restrict__ off, const int* __restrict__ csr,
                         float* __restrict__ s1)
{
    int n = blockIdx.x * blockDim.x + threadIdx.x;
    if (n >= NODES) return;
    int a = off[n], b = off[n + 1];
    float m[8];
    #pragma unroll
    for (int h = 0; h < 8; ++h) m[h] = -INFINITY;
    for (int i = a; i < b; ++i) {
        int e = csr[i];
        #pragma unroll
        for (int h = 0; h < 8; ++h) m[h] = fmaxf(m[h], s1[(size_t)e * 8 + h]);
    }
    float d[8] = {0.f, 0.f, 0.f, 0.f, 0.f, 0.f, 0.f, 0.f};
    for (int i = a; i < b; ++i) {
        int e = csr[i];
        #pragma unroll
        for (int h = 0; h < 8; ++h) {
            float ex = expf(s1[(size_t)e * 8 + h] - m[h]);
            s1[(size_t)e * 8 + h] = ex;
            d[h] += ex;
        }
    }
    #pragma unroll
    for (int h = 0; h < 8; ++h) d[h] = 1.f / d[h];
    for (int i = a; i < b; ++i) {
        int e = csr[i];
        #pragma unroll
        for (int h = 0; h < 8; ++h) s1[(size_t)e * 8 + h] *= d[h];
    }
}

// ---------------- layer 1 aggregation + bias + ELU (bf16 in/out) ----------------
__global__ __launch_bounds__(256)
void aggregate1(const int* __restrict__ ei, const int* __restrict__ off,
                const int* __restrict__ csr, const float* __restrict__ s1,
                const unsigned short* __restrict__ xl, const float* __restrict__ bias,
                unsigned short* __restrict__ hout)
{
    int n = blockIdx.x;
    int c = threadIdx.x;
    int hh = c >> 5;
    float acc = 0.f;
    int a = off[n], b = off[n + 1];
    for (int i = a; i < b; ++i) {
        int e = csr[i];
        int src = (e < NEDGE) ? ei[e] : (e - NEDGE);
        float alpha = s1[(size_t)e * 8 + hh];
        acc += alpha * bf2f(xl[(size_t)src * C1 + c]);
    }
    float v = acc + bias[c];
    v = v > 0.f ? v : (expf(v) - 1.f);
    hout[(size_t)n * C1 + c] = f2bf(v);
}

// ---------------- layer 2 edge logits: one wave per edge ----------------
__global__ __launch_bounds__(256)
void edge_logits2(const int* __restrict__ ei, const float* __restrict__ h2l,
                  const float* __restrict__ h2r, const float* __restrict__ att,
                  float* __restrict__ s2)
{
    int e = ((blockIdx.x * blockDim.x + threadIdx.x) >> 6);
    int lane = threadIdx.x & 63;
    if (e >= ETOT) return;
    int src, dst;
    if (e < NEDGE) { src = ei[e]; dst = ei[NEDGE + e]; }
    else           { src = e - NEDGE; dst = src; }
    float p = 0.f;
    if (lane < C2) {
        float v = h2l[(size_t)src * C2 + lane] + h2r[(size_t)dst * C2 + lane];
        p = lrelu(v) * att[lane];
    }
    #pragma unroll
    for (int o = 32; o > 0; o >>= 1) p += __shfl_xor(p, o);
    if (lane == 0) s2[e] = p;
}

// ---------------- layer 2 softmax (alpha in place) ----------------
__global__ void softmax2(const int* __restrict__ off, const int* __restrict__ csr,
                         float* __restrict__ s2)
{
    int n = blockIdx.x * blockDim.x + threadIdx.x;
    if (n >= NODES) return;
    int a = off[n], b = off[n + 1];
    float m = -INFINITY;
    for (int i = a; i < b; ++i) m = fmaxf(m, s2[csr[i]]);
    float d = 0.f;
    for (int i = a; i < b; ++i) {
        float ex = expf(s2[csr[i]] - m);
        s2[csr[i]] = ex;
        d += ex;
    }
    float inv = 1.f / d;
    for (int i = a; i < b; ++i) s2[csr[i]] *= inv;
}

// ---------------- layer 2 aggregation + bias + log_softmax ----------------
__global__ __launch_bounds__(64)
void aggregate2(const int* __restrict__ ei, const int* __restrict__ off,
                const int* __restrict__ csr, const float* __restrict__ s2,
                const float* __restrict__ h2l, const float* __restrict__ bias,
                float* __restrict__ out)
{
    int n = blockIdx.x;
    int c = threadIdx.x;   // 0..63, active 0..39
    float acc = 0.f;
    int a = off[n], b = off[n + 1];
    for (int i = a; i < b; ++i) {
        int e = csr[i];
        int src = (e < NEDGE) ? ei[e] : (e - NEDGE);
        float alpha = s2[e];
        if (c < C2) acc += alpha * h2l[(size_t)src * C2 + c];
    }
    float v = (c < C2) ? (acc + bias[c]) : -INFINITY;
    float mx = v;
    #pragma unroll
    for (int o = 32; o > 0; o >>= 1) mx = fmaxf(mx, __shfl_xor(mx, o));
    float ex = (c < C2) ? expf(v - mx) : 0.f;
    float s = ex;
    #pragma unroll
    for (int o = 32; o > 0; o >>= 1) s += __shfl_xor(s, o);
    if (c < C2) out[(size_t)n * C2 + c] = v - mx - logf(s);
}

extern "C" void kernel_launch(void* const* d_in, const int* in_sizes, int n_in,
                              void* d_out, int out_size, void* d_ws, size_t ws_size,
                              hipStream_t stream)
{
    const float* x     = (const float*)d_in[0];
    const int*   ei    = (const int*)  d_in[1];
    const float* W1l   = (const float*)d_in[2];
    const float* b1l   = (const float*)d_in[3];
    const float* W1r   = (const float*)d_in[4];
    const float* b1r   = (const float*)d_in[5];
    const float* att1  = (const float*)d_in[6];
    const float* bias1 = (const float*)d_in[7];
    const float* W2l   = (const float*)d_in[8];
    const float* b2l   = (const float*)d_in[9];
    const float* W2r   = (const float*)d_in[10];
    const float* b2r   = (const float*)d_in[11];
    const float* att2  = (const float*)d_in[12];
    const float* bias2 = (const float*)d_in[13];
    float* out = (float*)d_out;

    float* ws = (float*)d_ws;
    unsigned short* xl1 = (unsigned short*)ws;              // 12.8M bf16
    unsigned short* xr1 = (unsigned short*)(ws + 6400000);  // 12.8M bf16 (h later)
    float* s1 = ws + 12800000;                              // 3.6M f32
    int*   csr = (int*)(ws + 16400000);                     // 450K
    int*   off = csr + ETOT;                                // 50001
    int*   cnt = off + (NODES + 1);                         // 50000
    unsigned short* Wt1 = (unsigned short*)(ws + 17000000); // 512*256 bf16
    unsigned short* Wt2 = (unsigned short*)(ws + 17100000); // 80*256 bf16
    unsigned short* h = xr1;                                // layer-1 output, bf16
    float* h2l = ws;                                        // 2M f32 (over dead xl1)
    float* h2r = ws + 2000000;
    float* s2  = ws + 4000000;                              // 450K f32

    const int* dstRow = ei + NEDGE;

    // ---- CSR build (counting sort over dst) ----
    zero_int<<<(NODES + 255) / 256, 256, 0, stream>>>(cnt, NODES);
    count_kernel<<<(ETOT + 255) / 256, 256, 0, stream>>>(dstRow, cnt);
    scan_kernel<<<1, 1024, 0, stream>>>(cnt, off, NODES);
    zero_int<<<(NODES + 255) / 256, 256, 0, stream>>>(cnt, NODES);
    place_kernel<<<(ETOT + 255) / 256, 256, 0, stream>>>(dstRow, off, cnt, csr);

    // ---- weight prep ----
    prep_w<<<(512 * 256 + 255) / 256, 256, 0, stream>>>(W1l, W1r, Wt1, DIN, C1);
    prep_w<<<(80 * 256 + 255) / 256, 256, 0, stream>>>(W2l, W2r, Wt2, C1, C2);

    // ---- layer 1 ----
    {
        dim3 g((NODES + GBM - 1) / GBM, (2 * C1) / GBN);   // 391 x 4
        mfma_gemm<false, unsigned short><<<g, 256, 0, stream>>>(
            (const void*)x, Wt1, b1l, b1r, xl1, xr1, NODES, DIN, 2 * C1, C1);
    }
    edge_logits1<<<(ETOT + 3) / 4, 256, 0, stream>>>(ei, xl1, xr1, att1, s1);
    softmax1<<<(NODES + 255) / 256, 256, 0, stream>>>(off, csr, s1);
    aggregate1<<<NODES, 256, 0, stream>>>(ei, off, csr, s1, xl1, bias1, h);

    // ---- layer 2 ----
    {
        dim3 g((NODES + GBM - 1) / GBM, 1);                 // 391 x 1 (80 cols)
        mfma_gemm<true, float><<<g, 256, 0, stream>>>(
            (const void*)h, Wt2, b2l, b2r, h2l, h2r, NODES, C1, 2 * C2, C2);
    }
    edge_logits2<<<(ETOT + 3) / 4, 256, 0, stream>>>(ei, h2l, h2r, att2, s2);
    softmax2<<<(NODES + 255) / 256, 256, 0, stream>>>(off, csr, s2);
    aggregate2<<<NODES, 64, 0, stream>>>(ei, off, csr, s2, h2l, bias2, out);
}

// Round 3
// 584.598 us; speedup vs baseline: 1.6958x; 1.1757x over previous
//
#include <hip/hip_runtime.h>
#include <math.h>

#define NODES 50000
#define NEDGE 400000
#define ETOT  450000   // NEDGE + NODES self loops
#define DIN   256
#define C1    256      // heads*dh = 8*32
#define C2    40
#define KCAP  64       // edges cached per chunk (online softmax over chunks)

typedef __attribute__((ext_vector_type(8))) short bfrag;
typedef __attribute__((ext_vector_type(4))) float facc;

#define GPTR(p) (const __attribute__((address_space(1))) unsigned int*)(p)
#define LPTR(p) (__attribute__((address_space(3))) unsigned int*)(p)

static __device__ __forceinline__ float lrelu(float v) { return v > 0.f ? v : 0.2f * v; }

static __device__ __forceinline__ float bf2f(unsigned int u16) {
    unsigned int x = u16 << 16;
    float f;
    __builtin_memcpy(&f, &x, 4);
    return f;
}
static __device__ __forceinline__ unsigned short f2bf(float f) {
    unsigned int x;
    __builtin_memcpy(&x, &f, 4);
    unsigned int r = x + 0x7fffu + ((x >> 16) & 1u);   // RNE
    return (unsigned short)(r >> 16);
}

// ---------------- CSR build ----------------
__global__ void zero_int(int* p, int n) {
    int i = blockIdx.x * blockDim.x + threadIdx.x;
    if (i < n) p[i] = 0;
}

__global__ void count_kernel(const int* __restrict__ dstRow, int* __restrict__ cnt) {
    int e = blockIdx.x * blockDim.x + threadIdx.x;
    if (e >= ETOT) return;
    int d = (e < NEDGE) ? dstRow[e] : (e - NEDGE);
    atomicAdd(&cnt[d], 1);
}

__global__ void scan_kernel(const int* __restrict__ cnt, int* __restrict__ off, int n) {
    __shared__ int buf[1024];
    __shared__ int carry;
    int t = threadIdx.x;
    if (t == 0) carry = 0;
    __syncthreads();
    for (int base = 0; base < n; base += 1024) {
        int i = base + t;
        int v = (i < n) ? cnt[i] : 0;
        buf[t] = v;
        __syncthreads();
        for (int d = 1; d < 1024; d <<= 1) {
            int add = (t >= d) ? buf[t - d] : 0;
            __syncthreads();
            buf[t] += add;
            __syncthreads();
        }
        int incl = buf[t];
        int excl = incl - v;
        if (i < n) off[i] = carry + excl;
        __syncthreads();
        if (t == 1023) carry += incl;
        __syncthreads();
    }
    if (t == 0) off[n] = carry;
}

__global__ void place_kernel(const int* __restrict__ dstRow, const int* __restrict__ off,
                             int* __restrict__ cnt, int* __restrict__ csr) {
    int e = blockIdx.x * blockDim.x + threadIdx.x;
    if (e >= ETOT) return;
    int d = (e < NEDGE) ? dstRow[e] : (e - NEDGE);
    int slot = off[d] + atomicAdd(&cnt[d], 1);
    csr[slot] = e;
}

// ---------------- weight transpose+cast: Wt[n][k] = bf16(W[k][n]) ----------------
__global__ void prep_w(const float* __restrict__ Wl, const float* __restrict__ Wr,
                       unsigned short* __restrict__ Wt, int K, int Nhalf) {
    int idx = blockIdx.x * 256 + threadIdx.x;   // n*K + k
    int n = idx / K;
    int k = idx - n * K;
    if (n >= 2 * Nhalf) return;
    float v = (n < Nhalf) ? Wl[(size_t)k * Nhalf + n] : Wr[(size_t)k * Nhalf + (n - Nhalf)];
    Wt[idx] = f2bf(v);
}

// ---------------- MFMA dual GEMM ----------------
#define GBM 128
#define GBN 128
#define GBK 32

template<bool ABF16, typename OUTT>
__global__ __launch_bounds__(256)
void mfma_gemm(const void* __restrict__ Av, const unsigned short* __restrict__ Bt,
               const float* __restrict__ bl, const float* __restrict__ br,
               OUTT* __restrict__ Cl, OUTT* __restrict__ Cr,
               int M, int K, int Nrows, int Nhalf)
{
    __shared__ __align__(16) unsigned short As[GBM * GBK];
    __shared__ __align__(16) unsigned short Bs[GBN * GBK];

    const int tid  = threadIdx.x;
    const int lane = tid & 63;
    const int w    = tid >> 6;
    const int wr   = w >> 1;
    const int wc   = w & 1;
    const int row0 = blockIdx.x * GBM;
    const int col0 = blockIdx.y * GBN;

    facc acc[4][4];
    #pragma unroll
    for (int i = 0; i < 4; ++i)
        #pragma unroll
        for (int j = 0; j < 4; ++j) {
            facc z = {0.f, 0.f, 0.f, 0.f};
            acc[i][j] = z;
        }

    const int rA  = lane >> 2;
    const int sA  = lane & 3;
    const int kgA = sA ^ ((rA >> 1) & 3);

    for (int k0 = 0; k0 < K; k0 += GBK) {
        if (k0) __syncthreads();

        if constexpr (ABF16) {
            const unsigned short* Ab = (const unsigned short*)Av;
            #pragma unroll
            for (int p = 0; p < 2; ++p) {
                int chunk = p * 4 + w;
                int r_loc = chunk * 16 + rA;
                int grow  = row0 + r_loc;
                if (grow < M)
                    __builtin_amdgcn_global_load_lds(
                        GPTR(Ab + (size_t)grow * K + k0 + kgA * 8),
                        LPTR(As + chunk * 512), 16, 0, 0);
            }
        } else {
            const float* Af = (const float*)Av;
            #pragma unroll
            for (int p = 0; p < 2; ++p) {
                int r_loc = p * 64 + (tid >> 2);
                int g     = tid & 3;
                int grow  = row0 + r_loc;
                float v[8];
                if (grow < M) {
                    const float4* ap = (const float4*)(Af + (size_t)grow * K + k0 + g * 8);
                    float4 u0 = ap[0], u1 = ap[1];
                    v[0] = u0.x; v[1] = u0.y; v[2] = u0.z; v[3] = u0.w;
                    v[4] = u1.x; v[5] = u1.y; v[6] = u1.z; v[7] = u1.w;
                } else {
                    #pragma unroll
                    for (int j = 0; j < 8; ++j) v[j] = 0.f;
                }
                int slot = g ^ ((r_loc >> 1) & 3);
                bfrag pk;
                #pragma unroll
                for (int j = 0; j < 8; ++j) pk[j] = (short)f2bf(v[j]);
                *(bfrag*)(As + r_loc * 32 + slot * 8) = pk;
            }
        }

        #pragma unroll
        for (int p = 0; p < 2; ++p) {
            int chunk = p * 4 + w;
            int r_loc = chunk * 16 + rA;
            int grow  = col0 + r_loc;
            if (grow < Nrows)
                __builtin_amdgcn_global_load_lds(
                    GPTR(Bt + (size_t)grow * K + k0 + kgA * 8),
                    LPTR(Bs + chunk * 512), 16, 0, 0);
        }

        __syncthreads();

        const int fr    = lane & 15;
        const int sRead = (lane >> 4) ^ ((fr >> 1) & 3);
        bfrag af[4], bfv[4];
        #pragma unroll
        for (int mi = 0; mi < 4; ++mi)
            af[mi] = *(const bfrag*)(As + (wr * 64 + mi * 16 + fr) * 32 + sRead * 8);
        #pragma unroll
        for (int ni = 0; ni < 4; ++ni)
            bfv[ni] = *(const bfrag*)(Bs + (wc * 64 + ni * 16 + fr) * 32 + sRead * 8);
        #pragma unroll
        for (int mi = 0; mi < 4; ++mi)
            #pragma unroll
            for (int ni = 0; ni < 4; ++ni)
                acc[mi][ni] = __builtin_amdgcn_mfma_f32_16x16x32_bf16(
                    af[mi], bfv[ni], acc[mi][ni], 0, 0, 0);
    }

    #pragma unroll
    for (int mi = 0; mi < 4; ++mi) {
        const int rbase = row0 + wr * 64 + mi * 16 + ((lane >> 4) << 2);
        #pragma unroll
        for (int ni = 0; ni < 4; ++ni) {
            const int col = col0 + wc * 64 + ni * 16 + (lane & 15);
            #pragma unroll
            for (int rg = 0; rg < 4; ++rg) {
                int r = rbase + rg;
                if (r >= M) continue;
                float v = acc[mi][ni][rg];
                if (col < Nhalf) {
                    v += bl[col];
                    if constexpr (sizeof(OUTT) == 2)
                        Cl[(size_t)r * Nhalf + col] = (OUTT)f2bf(v);
                    else
                        Cl[(size_t)r * Nhalf + col] = (OUTT)v;
                } else if (col < 2 * Nhalf) {
                    int c2 = col - Nhalf;
                    v += br[c2];
                    if constexpr (sizeof(OUTT) == 2)
                        Cr[(size_t)r * Nhalf + c2] = (OUTT)f2bf(v);
                    else
                        Cr[(size_t)r * Nhalf + c2] = (OUTT)v;
                }
            }
        }
    }
}

// ---------------- fused layer 1: logits + online softmax + aggregate + ELU ----------------
__global__ __launch_bounds__(256)
void fused_l1(const int* __restrict__ ei, const int* __restrict__ off,
              const int* __restrict__ csr, const unsigned short* __restrict__ xl,
              const unsigned short* xr, const float* __restrict__ att,
              const float* __restrict__ bias, unsigned short* hout)
{
    __shared__ unsigned short cache[KCAP * C1];   // 32 KB
    __shared__ float sarr[KCAP][8];               // 2 KB
    __shared__ int   srcs[KCAP];
    __shared__ float mh[8], dh[8], rh[8];

    const int n    = blockIdx.x;
    const int tid  = threadIdx.x;
    const int lane = tid & 63;
    const int w    = tid >> 6;
    const int a = off[n], b = off[n + 1];

    if (tid < 8) { mh[tid] = -INFINITY; dh[tid] = 0.f; }

    // per-lane slice of this node's target transform + attention weights
    const uint2 xrn = *(const uint2*)(xr + (size_t)n * C1 + lane * 4);
    const float xr0 = bf2f(xrn.x & 0xffff), xr1v = bf2f(xrn.x >> 16);
    const float xr2 = bf2f(xrn.y & 0xffff), xr3  = bf2f(xrn.y >> 16);
    const float4 wv = *(const float4*)(att + lane * 4);

    float acc = 0.f;   // output channel = tid

    for (int start = a; start < b; start += KCAP) {
        const int cnt = min(KCAP, b - start);
        __syncthreads();   // protect LDS reuse from previous chunk's aggregation
        if (tid < cnt) {
            int e = csr[start + tid];
            srcs[tid] = (e < NEDGE) ? ei[e] : (e - NEDGE);
        }
        __syncthreads();

        // wave-parallel: logits + row caching (one 512B row per wave-edge)
        for (int i = w; i < cnt; i += 4) {
            const int src = srcs[i];
            const uint2 ua = *(const uint2*)(xl + (size_t)src * C1 + lane * 4);
            *(uint2*)(cache + i * C1 + lane * 4) = ua;
            float p = lrelu(bf2f(ua.x & 0xffff) + xr0) * wv.x
                    + lrelu(bf2f(ua.x >> 16)    + xr1v) * wv.y
                    + lrelu(bf2f(ua.y & 0xffff) + xr2) * wv.z
                    + lrelu(bf2f(ua.y >> 16)    + xr3) * wv.w;
            p += __shfl_xor(p, 1);
            p += __shfl_xor(p, 2);
            p += __shfl_xor(p, 4);
            if ((lane & 7) == 0) sarr[i][lane >> 3] = p;
        }
        __syncthreads();

        // online softmax stats per head
        if (tid < 8) {
            float cm = mh[tid];
            for (int i = 0; i < cnt; ++i) cm = fmaxf(cm, sarr[i][tid]);
            const float r = expf(mh[tid] - cm);   // 0 on first chunk (m=-inf)
            float s = 0.f;
            for (int i = 0; i < cnt; ++i) {
                float p = expf(sarr[i][tid] - cm);
                sarr[i][tid] = p;
                s += p;
            }
            dh[tid] = dh[tid] * r + s;
            rh[tid] = r;
            mh[tid] = cm;
        }
        __syncthreads();

        // aggregation (channel = tid)
        const float r = rh[tid >> 5];
        acc *= r;
        for (int i = 0; i < cnt; ++i)
            acc += sarr[i][tid >> 5] * bf2f(cache[i * C1 + tid]);
    }

    float v = acc / dh[tid >> 5] + bias[tid];
    v = v > 0.f ? v : (expf(v) - 1.f);
    hout[(size_t)n * C1 + tid] = f2bf(v);
}

// ---------------- fused layer 2: logits + online softmax + aggregate + log_softmax ----------------
__global__ __launch_bounds__(256)
void fused_l2(const int* __restrict__ ei, const int* __restrict__ off,
              const int* __restrict__ csr, const float* __restrict__ h2l,
              const float* __restrict__ h2r, const float* __restrict__ att,
              const float* __restrict__ bias, float* __restrict__ out)
{
    __shared__ float cache[KCAP * C2];   // 10 KB
    __shared__ float sarr[KCAP];
    __shared__ int   srcs[KCAP];
    __shared__ float mS, dS, rS;

    const int n    = blockIdx.x;
    const int tid  = threadIdx.x;
    const int lane = tid & 63;
    const int w    = tid >> 6;
    const int a = off[n], b = off[n + 1];

    if (tid == 0) { mS = -INFINITY; dS = 0.f; }

    const float xrn = (lane < C2) ? h2r[(size_t)n * C2 + lane] : 0.f;
    const float av  = (lane < C2) ? att[lane] : 0.f;

    float acc = 0.f;   // channel = tid (< C2 active)

    for (int start = a; start < b; start += KCAP) {
        const int cnt = min(KCAP, b - start);
        __syncthreads();
        if (tid < cnt) {
            int e = csr[start + tid];
            srcs[tid] = (e < NEDGE) ? ei[e] : (e - NEDGE);
        }
        __syncthreads();

        for (int i = w; i < cnt; i += 4) {
            const int src = srcs[i];
            float xv = 0.f, p = 0.f;
            if (lane < C2) {
                xv = h2l[(size_t)src * C2 + lane];
                cache[i * C2 + lane] = xv;
                p = lrelu(xv + xrn) * av;
            }
            #pragma unroll
            for (int o = 32; o; o >>= 1) p += __shfl_xor(p, o);
            if (lane == 0) sarr[i] = p;
        }
        __syncthreads();

        if (tid == 0) {
            float cm = mS;
            for (int i = 0; i < cnt; ++i) cm = fmaxf(cm, sarr[i]);
            const float r = expf(mS - cm);
            float s = 0.f;
            for (int i = 0; i < cnt; ++i) {
                float p = expf(sarr[i] - cm);
                sarr[i] = p;
                s += p;
            }
            dS = dS * r + s;
            rS = r;
            mS = cm;
        }
        __syncthreads();

        if (tid < C2) {
            acc *= rS;
            for (int i = 0; i < cnt; ++i)
                acc += sarr[i] * cache[i * C2 + tid];
        }
    }

    if (w == 0) {
        float v = (lane < C2) ? (acc / dS + bias[lane]) : -INFINITY;
        float mx = v;
        #pragma unroll
        for (int o = 32; o; o >>= 1) mx = fmaxf(mx, __shfl_xor(mx, o));
        float ex = (lane < C2) ? expf(v - mx) : 0.f;
        float s = ex;
        #pragma unroll
        for (int o = 32; o; o >>= 1) s += __shfl_xor(s, o);
        if (lane < C2) out[(size_t)n * C2 + lane] = v - mx - logf(s);
    }
}

extern "C" void kernel_launch(void* const* d_in, const int* in_sizes, int n_in,
                              void* d_out, int out_size, void* d_ws, size_t ws_size,
                              hipStream_t stream)
{
    const float* x     = (const float*)d_in[0];
    const int*   ei    = (const int*)  d_in[1];
    const float* W1l   = (const float*)d_in[2];
    const float* b1l   = (const float*)d_in[3];
    const float* W1r   = (const float*)d_in[4];
    const float* b1r   = (const float*)d_in[5];
    const float* att1  = (const float*)d_in[6];
    const float* bias1 = (const float*)d_in[7];
    const float* W2l   = (const float*)d_in[8];
    const float* b2l   = (const float*)d_in[9];
    const float* W2r   = (const float*)d_in[10];
    const float* b2r   = (const float*)d_in[11];
    const float* att2  = (const float*)d_in[12];
    const float* bias2 = (const float*)d_in[13];
    float* out = (float*)d_out;

    float* ws = (float*)d_ws;
    unsigned short* xl1 = (unsigned short*)ws;              // 12.8M bf16
    unsigned short* xr1 = (unsigned short*)(ws + 6400000);  // 12.8M bf16 (doubles as h)
    int*   csr = (int*)(ws + 16400000);
    int*   off = csr + ETOT;
    int*   cnt = off + (NODES + 1);
    unsigned short* Wt1 = (unsigned short*)(ws + 17000000);
    unsigned short* Wt2 = (unsigned short*)(ws + 17100000);
    unsigned short* h = xr1;                                // layer-1 output (in place over xr1)
    float* h2l = ws;                                        // 2M f32 (over dead xl1)
    float* h2r = ws + 2000000;

    const int* dstRow = ei + NEDGE;

    // ---- CSR build ----
    zero_int<<<(NODES + 255) / 256, 256, 0, stream>>>(cnt, NODES);
    count_kernel<<<(ETOT + 255) / 256, 256, 0, stream>>>(dstRow, cnt);
    scan_kernel<<<1, 1024, 0, stream>>>(cnt, off, NODES);
    zero_int<<<(NODES + 255) / 256, 256, 0, stream>>>(cnt, NODES);
    place_kernel<<<(ETOT + 255) / 256, 256, 0, stream>>>(dstRow, off, cnt, csr);

    // ---- weight prep ----
    prep_w<<<(512 * 256 + 255) / 256, 256, 0, stream>>>(W1l, W1r, Wt1, DIN, C1);
    prep_w<<<(80 * 256 + 255) / 256, 256, 0, stream>>>(W2l, W2r, Wt2, C1, C2);

    // ---- layer 1 ----
    {
        dim3 g((NODES + GBM - 1) / GBM, (2 * C1) / GBN);
        mfma_gemm<false, unsigned short><<<g, 256, 0, stream>>>(
            (const void*)x, Wt1, b1l, b1r, xl1, xr1, NODES, DIN, 2 * C1, C1);
    }
    fused_l1<<<NODES, 256, 0, stream>>>(ei, off, csr, xl1, xr1, att1, bias1, h);

    // ---- layer 2 ----
    {
        dim3 g((NODES + GBM - 1) / GBM, 1);
        mfma_gemm<true, float><<<g, 256, 0, stream>>>(
            (const void*)h, Wt2, b2l, b2r, h2l, h2r, NODES, C1, 2 * C2, C2);
    }
    fused_l2<<<NODES, 256, 0, stream>>>(ei, off, csr, h2l, h2r, att2, bias2, out);
}

// Round 4
// 376.043 us; speedup vs baseline: 2.6364x; 1.5546x over previous
//
#include <hip/hip_runtime.h>
#include <math.h>

#define NODES 50000
#define NEDGE 400000
#define ETOT  450000   // NEDGE + NODES self loops
#define DIN   256
#define C1    256      // heads*dh = 8*32
#define C2    40

typedef __attribute__((ext_vector_type(8))) short bfrag;
typedef __attribute__((ext_vector_type(4))) float facc;

#define GPTR(p) (const __attribute__((address_space(1))) unsigned int*)(p)
#define LPTR(p) (__attribute__((address_space(3))) unsigned int*)(p)

static __device__ __forceinline__ float lrelu(float v) { return v > 0.f ? v : 0.2f * v; }

static __device__ __forceinline__ float bf2f(unsigned int u16) {
    unsigned int x = u16 << 16;
    float f;
    __builtin_memcpy(&f, &x, 4);
    return f;
}
static __device__ __forceinline__ unsigned short f2bf(float f) {
    unsigned int x;
    __builtin_memcpy(&x, &f, 4);
    unsigned int r = x + 0x7fffu + ((x >> 16) & 1u);   // RNE
    return (unsigned short)(r >> 16);
}

// ---------------- CSR build ----------------
__global__ void zero_int(int* p, int n) {
    int i = blockIdx.x * blockDim.x + threadIdx.x;
    if (i < n) p[i] = 0;
}

__global__ void count_kernel(const int* __restrict__ dstRow, int* __restrict__ cnt) {
    int e = blockIdx.x * blockDim.x + threadIdx.x;
    if (e >= ETOT) return;
    int d = (e < NEDGE) ? dstRow[e] : (e - NEDGE);
    atomicAdd(&cnt[d], 1);
}

// single-pass scan: 1024 threads x 49 items
__global__ __launch_bounds__(1024)
void scan50k(const int* __restrict__ cnt, int* __restrict__ off, int* __restrict__ wrk) {
    __shared__ int sums[1024];
    const int t = threadIdx.x;
    const int ITEMS = (NODES + 1023) / 1024;   // 49
    const int base = t * ITEMS;
    const int end  = min(base + ITEMS, NODES);
    int s = 0;
    for (int i = base; i < end; ++i) s += cnt[i];
    sums[t] = s;
    __syncthreads();
    for (int d = 1; d < 1024; d <<= 1) {
        int add = (t >= d) ? sums[t - d] : 0;
        __syncthreads();
        sums[t] += add;
        __syncthreads();
    }
    int run = sums[t] - s;   // exclusive prefix
    for (int i = base; i < end; ++i) {
        off[i] = run;
        wrk[i] = run;
        run += cnt[i];
    }
    if (t == 1023) off[NODES] = sums[1023];
}

__global__ void place_kernel(const int* __restrict__ dstRow, int* __restrict__ wrk,
                             int* __restrict__ csr) {
    int e = blockIdx.x * blockDim.x + threadIdx.x;
    if (e >= ETOT) return;
    int d = (e < NEDGE) ? dstRow[e] : (e - NEDGE);
    int slot = atomicAdd(&wrk[d], 1);
    csr[slot] = e;
}

// ---------------- weight transpose+cast: Wt[n][k] = bf16(W[k][n]) ----------------
__global__ void prep_w(const float* __restrict__ Wl, const float* __restrict__ Wr,
                       unsigned short* __restrict__ Wt, int K, int Nhalf) {
    int idx = blockIdx.x * 256 + threadIdx.x;   // n*K + k
    int n = idx / K;
    int k = idx - n * K;
    if (n >= 2 * Nhalf) return;
    float v = (n < Nhalf) ? Wl[(size_t)k * Nhalf + n] : Wr[(size_t)k * Nhalf + (n - Nhalf)];
    Wt[idx] = f2bf(v);
}

// ---------------- MFMA dual GEMM ----------------
#define GBM 128
#define GBN 128
#define GBK 32

template<bool ABF16, typename OUTT>
__global__ __launch_bounds__(256)
void mfma_gemm(const void* __restrict__ Av, const unsigned short* __restrict__ Bt,
               const float* __restrict__ bl, const float* __restrict__ br,
               OUTT* __restrict__ Cl, OUTT* __restrict__ Cr,
               int M, int K, int Nrows, int Nhalf)
{
    __shared__ __align__(16) unsigned short As[GBM * GBK];
    __shared__ __align__(16) unsigned short Bs[GBN * GBK];

    const int tid  = threadIdx.x;
    const int lane = tid & 63;
    const int w    = tid >> 6;
    const int wr   = w >> 1;
    const int wc   = w & 1;
    const int row0 = blockIdx.x * GBM;
    const int col0 = blockIdx.y * GBN;

    facc acc[4][4];
    #pragma unroll
    for (int i = 0; i < 4; ++i)
        #pragma unroll
        for (int j = 0; j < 4; ++j) {
            facc z = {0.f, 0.f, 0.f, 0.f};
            acc[i][j] = z;
        }

    const int rA  = lane >> 2;
    const int sA  = lane & 3;
    const int kgA = sA ^ ((rA >> 1) & 3);

    for (int k0 = 0; k0 < K; k0 += GBK) {
        if (k0) __syncthreads();

        if constexpr (ABF16) {
            const unsigned short* Ab = (const unsigned short*)Av;
            #pragma unroll
            for (int p = 0; p < 2; ++p) {
                int chunk = p * 4 + w;
                int r_loc = chunk * 16 + rA;
                int grow  = row0 + r_loc;
                if (grow < M)
                    __builtin_amdgcn_global_load_lds(
                        GPTR(Ab + (size_t)grow * K + k0 + kgA * 8),
                        LPTR(As + chunk * 512), 16, 0, 0);
            }
        } else {
            const float* Af = (const float*)Av;
            #pragma unroll
            for (int p = 0; p < 2; ++p) {
                int r_loc = p * 64 + (tid >> 2);
                int g     = tid & 3;
                int grow  = row0 + r_loc;
                float v[8];
                if (grow < M) {
                    const float4* ap = (const float4*)(Af + (size_t)grow * K + k0 + g * 8);
                    float4 u0 = ap[0], u1 = ap[1];
                    v[0] = u0.x; v[1] = u0.y; v[2] = u0.z; v[3] = u0.w;
                    v[4] = u1.x; v[5] = u1.y; v[6] = u1.z; v[7] = u1.w;
                } else {
                    #pragma unroll
                    for (int j = 0; j < 8; ++j) v[j] = 0.f;
                }
                int slot = g ^ ((r_loc >> 1) & 3);
                bfrag pk;
                #pragma unroll
                for (int j = 0; j < 8; ++j) pk[j] = (short)f2bf(v[j]);
                *(bfrag*)(As + r_loc * 32 + slot * 8) = pk;
            }
        }

        #pragma unroll
        for (int p = 0; p < 2; ++p) {
            int chunk = p * 4 + w;
            int r_loc = chunk * 16 + rA;
            int grow  = col0 + r_loc;
            if (grow < Nrows)
                __builtin_amdgcn_global_load_lds(
                    GPTR(Bt + (size_t)grow * K + k0 + kgA * 8),
                    LPTR(Bs + chunk * 512), 16, 0, 0);
        }

        __syncthreads();

        const int fr    = lane & 15;
        const int sRead = (lane >> 4) ^ ((fr >> 1) & 3);
        bfrag af[4], bfv[4];
        #pragma unroll
        for (int mi = 0; mi < 4; ++mi)
            af[mi] = *(const bfrag*)(As + (wr * 64 + mi * 16 + fr) * 32 + sRead * 8);
        #pragma unroll
        for (int ni = 0; ni < 4; ++ni)
            bfv[ni] = *(const bfrag*)(Bs + (wc * 64 + ni * 16 + fr) * 32 + sRead * 8);
        #pragma unroll
        for (int mi = 0; mi < 4; ++mi)
            #pragma unroll
            for (int ni = 0; ni < 4; ++ni)
                acc[mi][ni] = __builtin_amdgcn_mfma_f32_16x16x32_bf16(
                    af[mi], bfv[ni], acc[mi][ni], 0, 0, 0);
    }

    #pragma unroll
    for (int mi = 0; mi < 4; ++mi) {
        const int rbase = row0 + wr * 64 + mi * 16 + ((lane >> 4) << 2);
        #pragma unroll
        for (int ni = 0; ni < 4; ++ni) {
            const int col = col0 + wc * 64 + ni * 16 + (lane & 15);
            #pragma unroll
            for (int rg = 0; rg < 4; ++rg) {
                int r = rbase + rg;
                if (r >= M) continue;
                float v = acc[mi][ni][rg];
                if (col < Nhalf) {
                    v += bl[col];
                    if constexpr (sizeof(OUTT) == 2)
                        Cl[(size_t)r * Nhalf + col] = (OUTT)f2bf(v);
                    else
                        Cl[(size_t)r * Nhalf + col] = (OUTT)v;
                } else if (col < 2 * Nhalf) {
                    int c2 = col - Nhalf;
                    v += br[c2];
                    if constexpr (sizeof(OUTT) == 2)
                        Cr[(size_t)r * Nhalf + c2] = (OUTT)f2bf(v);
                    else
                        Cr[(size_t)r * Nhalf + c2] = (OUTT)v;
                }
            }
        }
    }
}

// ---------------- fused layer 1: one WAVE per node, all-register online softmax ----------------
__global__ __launch_bounds__(256)
void fused_l1(const int* __restrict__ ei, const int* __restrict__ off,
              const int* __restrict__ csr, const unsigned short* __restrict__ xl,
              const unsigned short* xr, const float* __restrict__ att,
              const float* __restrict__ bias, unsigned short* hout)
{
    const int lane = threadIdx.x & 63;
    const int n    = blockIdx.x * 4 + (threadIdx.x >> 6);
    if (n >= NODES) return;

    const int a = off[n], b = off[n + 1];

    // this node's target-transform slice + attention weights (4 channels/lane)
    const uint2 xrn = *(const uint2*)(xr + (size_t)n * C1 + lane * 4);
    const float xr0 = bf2f(xrn.x & 0xffff), xr1v = bf2f(xrn.x >> 16);
    const float xr2 = bf2f(xrn.y & 0xffff), xr3  = bf2f(xrn.y >> 16);
    const float4 wv = *(const float4*)(att + lane * 4);

    float m = -INFINITY, d = 0.f;
    float a0 = 0.f, a1 = 0.f, a2 = 0.f, a3 = 0.f;

    for (int base = a; base < b; base += 64) {
        const int cn = min(64, b - base);
        // lane-parallel src resolution for this chunk
        int mySrc = 0;
        if (lane < cn) {
            int e = csr[base + lane];
            mySrc = (e < NEDGE) ? ei[e] : (e - NEDGE);
        }

        #define ROW1(i) (*(const uint2*)(xl + (size_t)__shfl(mySrc, min((i), cn - 1)) * C1 + lane * 4))
        #define PROC1(i, R)                                                         \
        {                                                                           \
            const float x0 = bf2f((R).x & 0xffff), x1 = bf2f((R).x >> 16);          \
            const float x2 = bf2f((R).y & 0xffff), x3 = bf2f((R).y >> 16);          \
            float p = lrelu(x0 + xr0) * wv.x + lrelu(x1 + xr1v) * wv.y              \
                    + lrelu(x2 + xr2) * wv.z + lrelu(x3 + xr3) * wv.w;              \
            p += __shfl_xor(p, 1);                                                  \
            p += __shfl_xor(p, 2);                                                  \
            p += __shfl_xor(p, 4);                                                  \
            const float mN = fmaxf(m, p);                                           \
            const float sc = expf(m - mN);                                          \
            const float wg = expf(p - mN);                                          \
            m = mN;                                                                 \
            d = d * sc + wg;                                                        \
            a0 = a0 * sc + wg * x0;                                                 \
            a1 = a1 * sc + wg * x1;                                                 \
            a2 = a2 * sc + wg * x2;                                                 \
            a3 = a3 * sc + wg * x3;                                                 \
        }

        uint2 r0, r1, r2, r3;
        r0 = ROW1(0);
        if (1 < cn) r1 = ROW1(1);
        if (2 < cn) r2 = ROW1(2);
        if (3 < cn) r3 = ROW1(3);
        for (int i = 0; i < cn; i += 4) {
            PROC1(i, r0);
            if (i + 4 < cn) r0 = ROW1(i + 4);
            if (i + 1 < cn) {
                PROC1(i + 1, r1);
                if (i + 5 < cn) r1 = ROW1(i + 5);
            }
            if (i + 2 < cn) {
                PROC1(i + 2, r2);
                if (i + 6 < cn) r2 = ROW1(i + 6);
            }
            if (i + 3 < cn) {
                PROC1(i + 3, r3);
                if (i + 7 < cn) r3 = ROW1(i + 7);
            }
        }
        #undef ROW1
        #undef PROC1
    }

    const float inv = 1.f / d;
    const float4 bv = *(const float4*)(bias + lane * 4);
    float v0 = a0 * inv + bv.x, v1 = a1 * inv + bv.y;
    float v2 = a2 * inv + bv.z, v3 = a3 * inv + bv.w;
    v0 = v0 > 0.f ? v0 : (expf(v0) - 1.f);
    v1 = v1 > 0.f ? v1 : (expf(v1) - 1.f);
    v2 = v2 > 0.f ? v2 : (expf(v2) - 1.f);
    v3 = v3 > 0.f ? v3 : (expf(v3) - 1.f);
    uint2 o;
    o.x = (unsigned int)f2bf(v0) | ((unsigned int)f2bf(v1) << 16);
    o.y = (unsigned int)f2bf(v2) | ((unsigned int)f2bf(v3) << 16);
    *(uint2*)(hout + (size_t)n * C1 + lane * 4) = o;
}

// ---------------- fused layer 2: one WAVE per node + log_softmax ----------------
__global__ __launch_bounds__(256)
void fused_l2(const int* __restrict__ ei, const int* __restrict__ off,
              const int* __restrict__ csr, const float* __restrict__ h2l,
              const float* __restrict__ h2r, const float* __restrict__ att,
              const float* __restrict__ bias, float* __restrict__ out)
{
    const int lane = threadIdx.x & 63;
    const int n    = blockIdx.x * 4 + (threadIdx.x >> 6);
    if (n >= NODES) return;

    const int a = off[n], b = off[n + 1];
    const bool act = lane < C2;

    const float xrn = act ? h2r[(size_t)n * C2 + lane] : 0.f;
    const float av  = act ? att[lane] : 0.f;

    float m = -INFINITY, d = 0.f, acc = 0.f;

    for (int base = a; base < b; base += 64) {
        const int cn = min(64, b - base);
        int mySrc = 0;
        if (lane < cn) {
            int e = csr[base + lane];
            mySrc = (e < NEDGE) ? ei[e] : (e - NEDGE);
        }

        #define ROW2(i) (act ? h2l[(size_t)__shfl(mySrc, min((i), cn - 1)) * C2 + lane] : 0.f)
        #define PROC2(i, R)                                                         \
        {                                                                           \
            float p = lrelu((R) + xrn) * av;                                        \
            p += __shfl_xor(p, 1);                                                  \
            p += __shfl_xor(p, 2);                                                  \
            p += __shfl_xor(p, 4);                                                  \
            p += __shfl_xor(p, 8);                                                  \
            p += __shfl_xor(p, 16);                                                 \
            p += __shfl_xor(p, 32);                                                 \
            const float mN = fmaxf(m, p);                                           \
            const float sc = expf(m - mN);                                          \
            const float wg = expf(p - mN);                                          \
            m = mN;                                                                 \
            d = d * sc + wg;                                                        \
            acc = acc * sc + wg * (R);                                              \
        }

        float r0, r1, r2, r3;
        r0 = ROW2(0);
        if (1 < cn) r1 = ROW2(1);
        if (2 < cn) r2 = ROW2(2);
        if (3 < cn) r3 = ROW2(3);
        for (int i = 0; i < cn; i += 4) {
            PROC2(i, r0);
            if (i + 4 < cn) r0 = ROW2(i + 4);
            if (i + 1 < cn) {
                PROC2(i + 1, r1);
                if (i + 5 < cn) r1 = ROW2(i + 5);
            }
            if (i + 2 < cn) {
                PROC2(i + 2, r2);
                if (i + 6 < cn) r2 = ROW2(i + 6);
            }
            if (i + 3 < cn) {
                PROC2(i + 3, r3);
                if (i + 7 < cn) r3 = ROW2(i + 7);
            }
        }
        #undef ROW2
        #undef PROC2
    }

    float v = act ? (acc / d + bias[lane]) : -INFINITY;
    float mx = v;
    #pragma unroll
    for (int o = 32; o; o >>= 1) mx = fmaxf(mx, __shfl_xor(mx, o));
    float ex = act ? expf(v - mx) : 0.f;
    float s = ex;
    #pragma unroll
    for (int o = 32; o; o >>= 1) s += __shfl_xor(s, o);
    if (act) out[(size_t)n * C2 + lane] = v - mx - logf(s);
}

extern "C" void kernel_launch(void* const* d_in, const int* in_sizes, int n_in,
                              void* d_out, int out_size, void* d_ws, size_t ws_size,
                              hipStream_t stream)
{
    const float* x     = (const float*)d_in[0];
    const int*   ei    = (const int*)  d_in[1];
    const float* W1l   = (const float*)d_in[2];
    const float* b1l   = (const float*)d_in[3];
    const float* W1r   = (const float*)d_in[4];
    const float* b1r   = (const float*)d_in[5];
    const float* att1  = (const float*)d_in[6];
    const float* bias1 = (const float*)d_in[7];
    const float* W2l   = (const float*)d_in[8];
    const float* b2l   = (const float*)d_in[9];
    const float* W2r   = (const float*)d_in[10];
    const float* b2r   = (const float*)d_in[11];
    const float* att2  = (const float*)d_in[12];
    const float* bias2 = (const float*)d_in[13];
    float* out = (float*)d_out;

    float* ws = (float*)d_ws;
    unsigned short* xl1 = (unsigned short*)ws;              // 12.8M bf16
    unsigned short* xr1 = (unsigned short*)(ws + 6400000);  // 12.8M bf16 (doubles as h)
    int*   csr = (int*)(ws + 16400000);
    int*   off = csr + ETOT;
    int*   cnt = off + (NODES + 1);
    int*   wrk = cnt + NODES;
    unsigned short* Wt1 = (unsigned short*)(ws + 17000064);
    unsigned short* Wt2 = (unsigned short*)(ws + 17100000);
    unsigned short* h = xr1;                                // layer-1 output (in place over xr1)
    float* h2l = ws;                                        // 2M f32 (over dead xl1)
    float* h2r = ws + 2000000;

    const int* dstRow = ei + NEDGE;

    // ---- CSR build ----
    zero_int<<<(NODES + 255) / 256, 256, 0, stream>>>(cnt, NODES);
    count_kernel<<<(ETOT + 255) / 256, 256, 0, stream>>>(dstRow, cnt);
    scan50k<<<1, 1024, 0, stream>>>(cnt, off, wrk);
    place_kernel<<<(ETOT + 255) / 256, 256, 0, stream>>>(dstRow, wrk, csr);

    // ---- weight prep ----
    prep_w<<<(512 * 256 + 255) / 256, 256, 0, stream>>>(W1l, W1r, Wt1, DIN, C1);
    prep_w<<<(80 * 256 + 255) / 256, 256, 0, stream>>>(W2l, W2r, Wt2, C1, C2);

    // ---- layer 1 ----
    {
        dim3 g((NODES + GBM - 1) / GBM, (2 * C1) / GBN);
        mfma_gemm<false, unsigned short><<<g, 256, 0, stream>>>(
            (const void*)x, Wt1, b1l, b1r, xl1, xr1, NODES, DIN, 2 * C1, C1);
    }
    fused_l1<<<(NODES + 3) / 4, 256, 0, stream>>>(ei, off, csr, xl1, xr1, att1, bias1, h);

    // ---- layer 2 ----
    {
        dim3 g((NODES + GBM - 1) / GBM, 1);
        mfma_gemm<true, float><<<g, 256, 0, stream>>>(
            (const void*)h, Wt2, b2l, b2r, h2l, h2r, NODES, C1, 2 * C2, C2);
    }
    fused_l2<<<(NODES + 3) / 4, 256, 0, stream>>>(ei, off, csr, h2l, h2r, att2, bias2, out);
}

// Round 5
// 277.027 us; speedup vs baseline: 3.5787x; 1.3574x over previous
//
#include <hip/hip_runtime.h>
#include <math.h>

#define NODES 50000
#define NEDGE 400000
#define ETOT  450000   // NEDGE + NODES self loops
#define DIN   256
#define C1    256      // heads*dh = 8*32
#define C2    40
#define SCAN_NB ((NODES + 255) / 256)   // 196

typedef __attribute__((ext_vector_type(8))) short bfrag;
typedef __attribute__((ext_vector_type(4))) float facc;

#define GPTR(p) (const __attribute__((address_space(1))) unsigned int*)(p)
#define LPTR(p) (__attribute__((address_space(3))) unsigned int*)(p)

static __device__ __forceinline__ float lrelu(float v) { return v > 0.f ? v : 0.2f * v; }

static __device__ __forceinline__ float bf2f(unsigned int u16) {
    unsigned int x = u16 << 16;
    float f;
    __builtin_memcpy(&f, &x, 4);
    return f;
}
static __device__ __forceinline__ unsigned short f2bf(float f) {
    unsigned int x;
    __builtin_memcpy(&x, &f, 4);
    unsigned int r = x + 0x7fffu + ((x >> 16) & 1u);   // RNE
    return (unsigned short)(r >> 16);
}

// ---------------- CSR build ----------------
__global__ void zero_int(int* p, int n) {
    int i = blockIdx.x * blockDim.x + threadIdx.x;
    if (i < n) p[i] = 0;
}

__global__ void count_kernel(const int* __restrict__ dstRow, int* __restrict__ cnt) {
    int e = blockIdx.x * blockDim.x + threadIdx.x;
    if (e >= ETOT) return;
    int d = (e < NEDGE) ? dstRow[e] : (e - NEDGE);
    atomicAdd(&cnt[d], 1);
}

// two-level parallel scan
__global__ __launch_bounds__(256)
void scan_blk(const int* __restrict__ cnt, int* __restrict__ off, int* __restrict__ blkTot) {
    __shared__ int buf[256];
    const int t = threadIdx.x;
    const int i = blockIdx.x * 256 + t;
    int v = (i < NODES) ? cnt[i] : 0;
    buf[t] = v;
    __syncthreads();
    #pragma unroll
    for (int d = 1; d < 256; d <<= 1) {
        int add = (t >= d) ? buf[t - d] : 0;
        __syncthreads();
        buf[t] += add;
        __syncthreads();
    }
    if (i < NODES) off[i] = buf[t] - v;   // local exclusive
    if (t == 255) blkTot[blockIdx.x] = buf[255];
}

__global__ __launch_bounds__(256)
void scan_top(const int* __restrict__ blkTot, int* __restrict__ blkOff, int* __restrict__ offEnd) {
    __shared__ int buf[256];
    const int t = threadIdx.x;
    int v = (t < SCAN_NB) ? blkTot[t] : 0;
    buf[t] = v;
    __syncthreads();
    #pragma unroll
    for (int d = 1; d < 256; d <<= 1) {
        int add = (t >= d) ? buf[t - d] : 0;
        __syncthreads();
        buf[t] += add;
        __syncthreads();
    }
    if (t < SCAN_NB) blkOff[t] = buf[t] - v;
    if (t == 255) *offEnd = buf[255];
}

__global__ __launch_bounds__(256)
void scan_fix(int* __restrict__ off, int* __restrict__ wrk, const int* __restrict__ blkOff) {
    const int i = blockIdx.x * 256 + threadIdx.x;
    if (i < NODES) {
        int v = off[i] + blkOff[blockIdx.x];
        off[i] = v;
        wrk[i] = v;
    }
}

__global__ void place_kernel(const int* __restrict__ dstRow, int* __restrict__ wrk,
                             int* __restrict__ csr) {
    int e = blockIdx.x * blockDim.x + threadIdx.x;
    if (e >= ETOT) return;
    int d = (e < NEDGE) ? dstRow[e] : (e - NEDGE);
    int slot = atomicAdd(&wrk[d], 1);
    csr[slot] = e;
}

// ---------------- weight transpose+cast: Wt[n][k] = bf16(W[k][n]) ----------------
__global__ void prep_w(const float* __restrict__ Wl, const float* __restrict__ Wr,
                       unsigned short* __restrict__ Wt, int K, int Nhalf) {
    int idx = blockIdx.x * 256 + threadIdx.x;   // n*K + k
    int n = idx / K;
    int k = idx - n * K;
    if (n >= 2 * Nhalf) return;
    float v = (n < Nhalf) ? Wl[(size_t)k * Nhalf + n] : Wr[(size_t)k * Nhalf + (n - Nhalf)];
    Wt[idx] = f2bf(v);
}

// ---------------- MFMA dual GEMM ----------------
#define GBM 128
#define GBN 128
#define GBK 32

template<bool ABF16, typename OUTT>
__global__ __launch_bounds__(256)
void mfma_gemm(const void* __restrict__ Av, const unsigned short* __restrict__ Bt,
               const float* __restrict__ bl, const float* __restrict__ br,
               OUTT* __restrict__ Cl, OUTT* __restrict__ Cr,
               int M, int K, int Nrows, int Nhalf)
{
    __shared__ __align__(16) unsigned short As[GBM * GBK];
    __shared__ __align__(16) unsigned short Bs[GBN * GBK];

    const int tid  = threadIdx.x;
    const int lane = tid & 63;
    const int w    = tid >> 6;
    const int wr   = w >> 1;
    const int wc   = w & 1;
    const int row0 = blockIdx.x * GBM;
    const int col0 = blockIdx.y * GBN;

    facc acc[4][4];
    #pragma unroll
    for (int i = 0; i < 4; ++i)
        #pragma unroll
        for (int j = 0; j < 4; ++j) {
            facc z = {0.f, 0.f, 0.f, 0.f};
            acc[i][j] = z;
        }

    const int rA  = lane >> 2;
    const int sA  = lane & 3;
    const int kgA = sA ^ ((rA >> 1) & 3);

    for (int k0 = 0; k0 < K; k0 += GBK) {
        if (k0) __syncthreads();

        if constexpr (ABF16) {
            const unsigned short* Ab = (const unsigned short*)Av;
            #pragma unroll
            for (int p = 0; p < 2; ++p) {
                int chunk = p * 4 + w;
                int r_loc = chunk * 16 + rA;
                int grow  = row0 + r_loc;
                if (grow < M)
                    __builtin_amdgcn_global_load_lds(
                        GPTR(Ab + (size_t)grow * K + k0 + kgA * 8),
                        LPTR(As + chunk * 512), 16, 0, 0);
            }
        } else {
            const float* Af = (const float*)Av;
            #pragma unroll
            for (int p = 0; p < 2; ++p) {
                int r_loc = p * 64 + (tid >> 2);
                int g     = tid & 3;
                int grow  = row0 + r_loc;
                float v[8];
                if (grow < M) {
                    const float4* ap = (const float4*)(Af + (size_t)grow * K + k0 + g * 8);
                    float4 u0 = ap[0], u1 = ap[1];
                    v[0] = u0.x; v[1] = u0.y; v[2] = u0.z; v[3] = u0.w;
                    v[4] = u1.x; v[5] = u1.y; v[6] = u1.z; v[7] = u1.w;
                } else {
                    #pragma unroll
                    for (int j = 0; j < 8; ++j) v[j] = 0.f;
                }
                int slot = g ^ ((r_loc >> 1) & 3);
                bfrag pk;
                #pragma unroll
                for (int j = 0; j < 8; ++j) pk[j] = (short)f2bf(v[j]);
                *(bfrag*)(As + r_loc * 32 + slot * 8) = pk;
            }
        }

        #pragma unroll
        for (int p = 0; p < 2; ++p) {
            int chunk = p * 4 + w;
            int r_loc = chunk * 16 + rA;
            int grow  = col0 + r_loc;
            if (grow < Nrows)
                __builtin_amdgcn_global_load_lds(
                    GPTR(Bt + (size_t)grow * K + k0 + kgA * 8),
                    LPTR(Bs + chunk * 512), 16, 0, 0);
        }

        __syncthreads();

        const int fr    = lane & 15;
        const int sRead = (lane >> 4) ^ ((fr >> 1) & 3);
        bfrag af[4], bfv[4];
        #pragma unroll
        for (int mi = 0; mi < 4; ++mi)
            af[mi] = *(const bfrag*)(As + (wr * 64 + mi * 16 + fr) * 32 + sRead * 8);
        #pragma unroll
        for (int ni = 0; ni < 4; ++ni)
            bfv[ni] = *(const bfrag*)(Bs + (wc * 64 + ni * 16 + fr) * 32 + sRead * 8);
        #pragma unroll
        for (int mi = 0; mi < 4; ++mi)
            #pragma unroll
            for (int ni = 0; ni < 4; ++ni)
                acc[mi][ni] = __builtin_amdgcn_mfma_f32_16x16x32_bf16(
                    af[mi], bfv[ni], acc[mi][ni], 0, 0, 0);
    }

    #pragma unroll
    for (int mi = 0; mi < 4; ++mi) {
        const int rbase = row0 + wr * 64 + mi * 16 + ((lane >> 4) << 2);
        #pragma unroll
        for (int ni = 0; ni < 4; ++ni) {
            const int col = col0 + wc * 64 + ni * 16 + (lane & 15);
            #pragma unroll
            for (int rg = 0; rg < 4; ++rg) {
                int r = rbase + rg;
                if (r >= M) continue;
                float v = acc[mi][ni][rg];
                if (col < Nhalf) {
                    v += bl[col];
                    if constexpr (sizeof(OUTT) == 2)
                        Cl[(size_t)r * Nhalf + col] = (OUTT)f2bf(v);
                    else
                        Cl[(size_t)r * Nhalf + col] = (OUTT)v;
                } else if (col < 2 * Nhalf) {
                    int c2 = col - Nhalf;
                    v += br[c2];
                    if constexpr (sizeof(OUTT) == 2)
                        Cr[(size_t)r * Nhalf + c2] = (OUTT)f2bf(v);
                    else
                        Cr[(size_t)r * Nhalf + c2] = (OUTT)v;
                }
            }
        }
    }
}

// ---------------- fused layer 1: one WAVE per node, all-register online softmax ----------------
__global__ __launch_bounds__(256)
void fused_l1(const int* __restrict__ ei, const int* __restrict__ off,
              const int* __restrict__ csr, const unsigned short* __restrict__ xl,
              const unsigned short* xr, const float* __restrict__ att,
              const float* __restrict__ bias, unsigned short* hout)
{
    const int lane = threadIdx.x & 63;
    const int n    = blockIdx.x * 4 + (threadIdx.x >> 6);
    if (n >= NODES) return;

    const int a = off[n], b = off[n + 1];

    const uint2 xrn = *(const uint2*)(xr + (size_t)n * C1 + lane * 4);
    const float xr0 = bf2f(xrn.x & 0xffff), xr1v = bf2f(xrn.x >> 16);
    const float xr2 = bf2f(xrn.y & 0xffff), xr3  = bf2f(xrn.y >> 16);
    const float4 wv = *(const float4*)(att + lane * 4);

    float m = -INFINITY, d = 0.f;
    float a0 = 0.f, a1 = 0.f, a2 = 0.f, a3 = 0.f;

    for (int base = a; base < b; base += 64) {
        const int cn = min(64, b - base);
        int mySrc = 0;
        if (lane < cn) {
            int e = csr[base + lane];
            mySrc = (e < NEDGE) ? ei[e] : (e - NEDGE);
        }

        #define ROW1(i) (*(const uint2*)(xl + (size_t)__shfl(mySrc, min((i), cn - 1)) * C1 + lane * 4))
        #define PROC1(i, R)                                                         \
        {                                                                           \
            const float x0 = bf2f((R).x & 0xffff), x1 = bf2f((R).x >> 16);          \
            const float x2 = bf2f((R).y & 0xffff), x3 = bf2f((R).y >> 16);          \
            float p = lrelu(x0 + xr0) * wv.x + lrelu(x1 + xr1v) * wv.y              \
                    + lrelu(x2 + xr2) * wv.z + lrelu(x3 + xr3) * wv.w;              \
            p += __shfl_xor(p, 1);                                                  \
            p += __shfl_xor(p, 2);                                                  \
            p += __shfl_xor(p, 4);                                                  \
            const float mN = fmaxf(m, p);                                           \
            const float sc = expf(m - mN);                                          \
            const float wg = expf(p - mN);                                          \
            m = mN;                                                                 \
            d = d * sc + wg;                                                        \
            a0 = a0 * sc + wg * x0;                                                 \
            a1 = a1 * sc + wg * x1;                                                 \
            a2 = a2 * sc + wg * x2;                                                 \
            a3 = a3 * sc + wg * x3;                                                 \
        }

        uint2 r0, r1, r2, r3;
        r0 = ROW1(0);
        if (1 < cn) r1 = ROW1(1);
        if (2 < cn) r2 = ROW1(2);
        if (3 < cn) r3 = ROW1(3);
        for (int i = 0; i < cn; i += 4) {
            PROC1(i, r0);
            if (i + 4 < cn) r0 = ROW1(i + 4);
            if (i + 1 < cn) {
                PROC1(i + 1, r1);
                if (i + 5 < cn) r1 = ROW1(i + 5);
            }
            if (i + 2 < cn) {
                PROC1(i + 2, r2);
                if (i + 6 < cn) r2 = ROW1(i + 6);
            }
            if (i + 3 < cn) {
                PROC1(i + 3, r3);
                if (i + 7 < cn) r3 = ROW1(i + 7);
            }
        }
        #undef ROW1
        #undef PROC1
    }

    const float inv = 1.f / d;
    const float4 bv = *(const float4*)(bias + lane * 4);
    float v0 = a0 * inv + bv.x, v1 = a1 * inv + bv.y;
    float v2 = a2 * inv + bv.z, v3 = a3 * inv + bv.w;
    v0 = v0 > 0.f ? v0 : (expf(v0) - 1.f);
    v1 = v1 > 0.f ? v1 : (expf(v1) - 1.f);
    v2 = v2 > 0.f ? v2 : (expf(v2) - 1.f);
    v3 = v3 > 0.f ? v3 : (expf(v3) - 1.f);
    uint2 o;
    o.x = (unsigned int)f2bf(v0) | ((unsigned int)f2bf(v1) << 16);
    o.y = (unsigned int)f2bf(v2) | ((unsigned int)f2bf(v3) << 16);
    *(uint2*)(hout + (size_t)n * C1 + lane * 4) = o;
}

// ---------------- fused layer 2: one WAVE per node + log_softmax ----------------
__global__ __launch_bounds__(256)
void fused_l2(const int* __restrict__ ei, const int* __restrict__ off,
              const int* __restrict__ csr, const float* __restrict__ h2l,
              const float* __restrict__ h2r, const float* __restrict__ att,
              const float* __restrict__ bias, float* __restrict__ out)
{
    const int lane = threadIdx.x & 63;
    const int n    = blockIdx.x * 4 + (threadIdx.x >> 6);
    if (n >= NODES) return;

    const int a = off[n], b = off[n + 1];
    const bool act = lane < C2;

    const float xrn = act ? h2r[(size_t)n * C2 + lane] : 0.f;
    const float av  = act ? att[lane] : 0.f;

    float m = -INFINITY, d = 0.f, acc = 0.f;

    for (int base = a; base < b; base += 64) {
        const int cn = min(64, b - base);
        int mySrc = 0;
        if (lane < cn) {
            int e = csr[base + lane];
            mySrc = (e < NEDGE) ? ei[e] : (e - NEDGE);
        }

        #define ROW2(i) (act ? h2l[(size_t)__shfl(mySrc, min((i), cn - 1)) * C2 + lane] : 0.f)
        #define PROC2(i, R)                                                         \
        {                                                                           \
            float p = lrelu((R) + xrn) * av;                                        \
            p += __shfl_xor(p, 1);                                                  \
            p += __shfl_xor(p, 2);                                                  \
            p += __shfl_xor(p, 4);                                                  \
            p += __shfl_xor(p, 8);                                                  \
            p += __shfl_xor(p, 16);                                                 \
            p += __shfl_xor(p, 32);                                                 \
            const float mN = fmaxf(m, p);                                           \
            const float sc = expf(m - mN);                                          \
            const float wg = expf(p - mN);                                          \
            m = mN;                                                                 \
            d = d * sc + wg;                                                        \
            acc = acc * sc + wg * (R);                                              \
        }

        float r0, r1, r2, r3;
        r0 = ROW2(0);
        if (1 < cn) r1 = ROW2(1);
        if (2 < cn) r2 = ROW2(2);
        if (3 < cn) r3 = ROW2(3);
        for (int i = 0; i < cn; i += 4) {
            PROC2(i, r0);
            if (i + 4 < cn) r0 = ROW2(i + 4);
            if (i + 1 < cn) {
                PROC2(i + 1, r1);
                if (i + 5 < cn) r1 = ROW2(i + 5);
            }
            if (i + 2 < cn) {
                PROC2(i + 2, r2);
                if (i + 6 < cn) r2 = ROW2(i + 6);
            }
            if (i + 3 < cn) {
                PROC2(i + 3, r3);
                if (i + 7 < cn) r3 = ROW2(i + 7);
            }
        }
        #undef ROW2
        #undef PROC2
    }

    float v = act ? (acc / d + bias[lane]) : -INFINITY;
    float mx = v;
    #pragma unroll
    for (int o = 32; o; o >>= 1) mx = fmaxf(mx, __shfl_xor(mx, o));
    float ex = act ? expf(v - mx) : 0.f;
    float s = ex;
    #pragma unroll
    for (int o = 32; o; o >>= 1) s += __shfl_xor(s, o);
    if (act) out[(size_t)n * C2 + lane] = v - mx - logf(s);
}

extern "C" void kernel_launch(void* const* d_in, const int* in_sizes, int n_in,
                              void* d_out, int out_size, void* d_ws, size_t ws_size,
                              hipStream_t stream)
{
    const float* x     = (const float*)d_in[0];
    const int*   ei    = (const int*)  d_in[1];
    const float* W1l   = (const float*)d_in[2];
    const float* b1l   = (const float*)d_in[3];
    const float* W1r   = (const float*)d_in[4];
    const float* b1r   = (const float*)d_in[5];
    const float* att1  = (const float*)d_in[6];
    const float* bias1 = (const float*)d_in[7];
    const float* W2l   = (const float*)d_in[8];
    const float* b2l   = (const float*)d_in[9];
    const float* W2r   = (const float*)d_in[10];
    const float* b2r   = (const float*)d_in[11];
    const float* att2  = (const float*)d_in[12];
    const float* bias2 = (const float*)d_in[13];
    float* out = (float*)d_out;

    float* ws = (float*)d_ws;
    unsigned short* xl1 = (unsigned short*)ws;              // 12.8M bf16
    unsigned short* xr1 = (unsigned short*)(ws + 6400000);  // 12.8M bf16 (doubles as h)
    int*   csr = (int*)(ws + 16400000);
    int*   off = csr + ETOT;
    int*   cnt = off + (NODES + 1);
    int*   wrk = cnt + NODES;
    int*   blkTot = wrk + NODES;
    int*   blkOff = blkTot + SCAN_NB;
    unsigned short* Wt1 = (unsigned short*)(ws + 17000064);
    unsigned short* Wt2 = (unsigned short*)(ws + 17100000);
    unsigned short* h = xr1;                                // layer-1 output (in place over xr1)
    float* h2l = ws;                                        // 2M f32 (over dead xl1)
    float* h2r = ws + 2000000;

    const int* dstRow = ei + NEDGE;

    // ---- CSR build ----
    zero_int<<<(NODES + 255) / 256, 256, 0, stream>>>(cnt, NODES);
    count_kernel<<<(ETOT + 255) / 256, 256, 0, stream>>>(dstRow, cnt);
    scan_blk<<<SCAN_NB, 256, 0, stream>>>(cnt, off, blkTot);
    scan_top<<<1, 256, 0, stream>>>(blkTot, blkOff, off + NODES);
    scan_fix<<<SCAN_NB, 256, 0, stream>>>(off, wrk, blkOff);
    place_kernel<<<(ETOT + 255) / 256, 256, 0, stream>>>(dstRow, wrk, csr);

    // ---- weight prep ----
    prep_w<<<(512 * 256 + 255) / 256, 256, 0, stream>>>(W1l, W1r, Wt1, DIN, C1);
    prep_w<<<(80 * 256 + 255) / 256, 256, 0, stream>>>(W2l, W2r, Wt2, C1, C2);

    // ---- layer 1 ----
    {
        dim3 g((NODES + GBM - 1) / GBM, (2 * C1) / GBN);
        mfma_gemm<false, unsigned short><<<g, 256, 0, stream>>>(
            (const void*)x, Wt1, b1l, b1r, xl1, xr1, NODES, DIN, 2 * C1, C1);
    }
    fused_l1<<<(NODES + 3) / 4, 256, 0, stream>>>(ei, off, csr, xl1, xr1, att1, bias1, h);

    // ---- layer 2 ----
    {
        dim3 g((NODES + GBM - 1) / GBM, 1);
        mfma_gemm<true, float><<<g, 256, 0, stream>>>(
            (const void*)h, Wt2, b2l, b2r, h2l, h2r, NODES, C1, 2 * C2, C2);
    }
    fused_l2<<<(NODES + 3) / 4, 256, 0, stream>>>(ei, off, csr, h2l, h2r, att2, bias2, out);
}

// Round 6
// 267.843 us; speedup vs baseline: 3.7014x; 1.0343x over previous
//
#include <hip/hip_runtime.h>
#include <math.h>

#define NODES 50000
#define NEDGE 400000
#define ETOT  450000   // NEDGE + NODES self loops
#define DIN   256
#define C1    256      // heads*dh = 8*32
#define C2    40
#define SCAN_NB ((NODES + 255) / 256)   // 196

typedef __attribute__((ext_vector_type(8))) short bfrag;
typedef __attribute__((ext_vector_type(4))) float facc;

#define GPTR(p) (const __attribute__((address_space(1))) unsigned int*)(p)
#define LPTR(p) (__attribute__((address_space(3))) unsigned int*)(p)

static __device__ __forceinline__ float lrelu(float v) { return v > 0.f ? v : 0.2f * v; }

static __device__ __forceinline__ float bf2f(unsigned int u16) {
    unsigned int x = u16 << 16;
    float f;
    __builtin_memcpy(&f, &x, 4);
    return f;
}
static __device__ __forceinline__ unsigned short f2bf(float f) {
    unsigned int x;
    __builtin_memcpy(&x, &f, 4);
    unsigned int r = x + 0x7fffu + ((x >> 16) & 1u);   // RNE
    return (unsigned short)(r >> 16);
}

// ---------------- f32 -> bf16 bulk convert (8 elems/thread) ----------------
__global__ __launch_bounds__(256)
void cvt_bf16(const float* __restrict__ in, unsigned short* __restrict__ out, int n8) {
    int i = blockIdx.x * 256 + threadIdx.x;
    if (i >= n8) return;
    const float4* p = (const float4*)in + (size_t)i * 2;
    float4 u0 = p[0], u1 = p[1];
    bfrag pk;
    pk[0] = (short)f2bf(u0.x); pk[1] = (short)f2bf(u0.y);
    pk[2] = (short)f2bf(u0.z); pk[3] = (short)f2bf(u0.w);
    pk[4] = (short)f2bf(u1.x); pk[5] = (short)f2bf(u1.y);
    pk[6] = (short)f2bf(u1.z); pk[7] = (short)f2bf(u1.w);
    *(bfrag*)(out + (size_t)i * 8) = pk;
}

// ---------------- CSR build ----------------
__global__ void zero_int(int* p, int n) {
    int i = blockIdx.x * blockDim.x + threadIdx.x;
    if (i < n) p[i] = 0;
}

__global__ void count_kernel(const int* __restrict__ dstRow, int* __restrict__ cnt) {
    int e = blockIdx.x * blockDim.x + threadIdx.x;
    if (e >= ETOT) return;
    int d = (e < NEDGE) ? dstRow[e] : (e - NEDGE);
    atomicAdd(&cnt[d], 1);
}

// two-level parallel scan
__global__ __launch_bounds__(256)
void scan_blk(const int* __restrict__ cnt, int* __restrict__ off, int* __restrict__ blkTot) {
    __shared__ int buf[256];
    const int t = threadIdx.x;
    const int i = blockIdx.x * 256 + t;
    int v = (i < NODES) ? cnt[i] : 0;
    buf[t] = v;
    __syncthreads();
    #pragma unroll
    for (int d = 1; d < 256; d <<= 1) {
        int add = (t >= d) ? buf[t - d] : 0;
        __syncthreads();
        buf[t] += add;
        __syncthreads();
    }
    if (i < NODES) off[i] = buf[t] - v;   // local exclusive
    if (t == 255) blkTot[blockIdx.x] = buf[255];
}

__global__ __launch_bounds__(256)
void scan_top(const int* __restrict__ blkTot, int* __restrict__ blkOff, int* __restrict__ offEnd) {
    __shared__ int buf[256];
    const int t = threadIdx.x;
    int v = (t < SCAN_NB) ? blkTot[t] : 0;
    buf[t] = v;
    __syncthreads();
    #pragma unroll
    for (int d = 1; d < 256; d <<= 1) {
        int add = (t >= d) ? buf[t - d] : 0;
        __syncthreads();
        buf[t] += add;
        __syncthreads();
    }
    if (t < SCAN_NB) blkOff[t] = buf[t] - v;
    if (t == 255) *offEnd = buf[255];
}

__global__ __launch_bounds__(256)
void scan_fix(int* __restrict__ off, int* __restrict__ wrk, const int* __restrict__ blkOff) {
    const int i = blockIdx.x * 256 + threadIdx.x;
    if (i < NODES) {
        int v = off[i] + blkOff[blockIdx.x];
        off[i] = v;
        wrk[i] = v;
    }
}

__global__ void place_kernel(const int* __restrict__ dstRow, int* __restrict__ wrk,
                             int* __restrict__ csr) {
    int e = blockIdx.x * blockDim.x + threadIdx.x;
    if (e >= ETOT) return;
    int d = (e < NEDGE) ? dstRow[e] : (e - NEDGE);
    int slot = atomicAdd(&wrk[d], 1);
    csr[slot] = e;
}

// ---------------- weight transpose+cast: Wt[n][k] = bf16(W[k][n]) ----------------
__global__ void prep_w(const float* __restrict__ Wl, const float* __restrict__ Wr,
                       unsigned short* __restrict__ Wt, int K, int Nhalf) {
    int idx = blockIdx.x * 256 + threadIdx.x;   // n*K + k
    int n = idx / K;
    int k = idx - n * K;
    if (n >= 2 * Nhalf) return;
    float v = (n < Nhalf) ? Wl[(size_t)k * Nhalf + n] : Wr[(size_t)k * Nhalf + (n - Nhalf)];
    Wt[idx] = f2bf(v);
}

// ---------------- MFMA dual GEMM (bf16 A via global_load_lds) ----------------
#define GBM 128
#define GBN 128
#define GBK 32

template<typename OUTT>
__global__ __launch_bounds__(256)
void mfma_gemm(const unsigned short* __restrict__ Ab, const unsigned short* __restrict__ Bt,
               const float* __restrict__ bl, const float* __restrict__ br,
               OUTT* __restrict__ Cl, OUTT* __restrict__ Cr,
               int M, int K, int Nrows, int Nhalf, int nbnShift)
{
    __shared__ __align__(16) unsigned short As[GBM * GBK];
    __shared__ __align__(16) unsigned short Bs[GBN * GBK];

    const int tid  = threadIdx.x;
    const int lane = tid & 63;
    const int w    = tid >> 6;
    const int wr   = w >> 1;
    const int wc   = w & 1;
    // column-block-fastest 1D grid: blocks sharing an A panel are dispatch-adjacent
    const int bx   = blockIdx.x >> nbnShift;
    const int by   = blockIdx.x & ((1 << nbnShift) - 1);
    const int row0 = bx * GBM;
    const int col0 = by * GBN;

    facc acc[4][4];
    #pragma unroll
    for (int i = 0; i < 4; ++i)
        #pragma unroll
        for (int j = 0; j < 4; ++j) {
            facc z = {0.f, 0.f, 0.f, 0.f};
            acc[i][j] = z;
        }

    const int rA  = lane >> 2;            // row within 16-row chunk
    const int sA  = lane & 3;             // 16B slot within 64B row
    const int kgA = sA ^ ((rA >> 1) & 3); // pre-swizzled source k-group

    for (int k0 = 0; k0 < K; k0 += GBK) {
        if (k0) __syncthreads();

        #pragma unroll
        for (int p = 0; p < 2; ++p) {
            int chunk = p * 4 + w;
            int r_loc = chunk * 16 + rA;
            int grow  = row0 + r_loc;
            if (grow < M)
                __builtin_amdgcn_global_load_lds(
                    GPTR(Ab + (size_t)grow * K + k0 + kgA * 8),
                    LPTR(As + chunk * 512), 16, 0, 0);
        }
        #pragma unroll
        for (int p = 0; p < 2; ++p) {
            int chunk = p * 4 + w;
            int r_loc = chunk * 16 + rA;
            int grow  = col0 + r_loc;
            if (grow < Nrows)
                __builtin_amdgcn_global_load_lds(
                    GPTR(Bt + (size_t)grow * K + k0 + kgA * 8),
                    LPTR(Bs + chunk * 512), 16, 0, 0);
        }

        __syncthreads();

        const int fr    = lane & 15;
        const int sRead = (lane >> 4) ^ ((fr >> 1) & 3);
        bfrag af[4], bfv[4];
        #pragma unroll
        for (int mi = 0; mi < 4; ++mi)
            af[mi] = *(const bfrag*)(As + (wr * 64 + mi * 16 + fr) * 32 + sRead * 8);
        #pragma unroll
        for (int ni = 0; ni < 4; ++ni)
            bfv[ni] = *(const bfrag*)(Bs + (wc * 64 + ni * 16 + fr) * 32 + sRead * 8);
        #pragma unroll
        for (int mi = 0; mi < 4; ++mi)
            #pragma unroll
            for (int ni = 0; ni < 4; ++ni)
                acc[mi][ni] = __builtin_amdgcn_mfma_f32_16x16x32_bf16(
                    af[mi], bfv[ni], acc[mi][ni], 0, 0, 0);
    }

    #pragma unroll
    for (int mi = 0; mi < 4; ++mi) {
        const int rbase = row0 + wr * 64 + mi * 16 + ((lane >> 4) << 2);
        #pragma unroll
        for (int ni = 0; ni < 4; ++ni) {
            const int col = col0 + wc * 64 + ni * 16 + (lane & 15);
            #pragma unroll
            for (int rg = 0; rg < 4; ++rg) {
                int r = rbase + rg;
                if (r >= M) continue;
                float v = acc[mi][ni][rg];
                if (col < Nhalf) {
                    v += bl[col];
                    if constexpr (sizeof(OUTT) == 2)
                        Cl[(size_t)r * Nhalf + col] = (OUTT)f2bf(v);
                    else
                        Cl[(size_t)r * Nhalf + col] = (OUTT)v;
                } else if (col < 2 * Nhalf) {
                    int c2 = col - Nhalf;
                    v += br[c2];
                    if constexpr (sizeof(OUTT) == 2)
                        Cr[(size_t)r * Nhalf + c2] = (OUTT)f2bf(v);
                    else
                        Cr[(size_t)r * Nhalf + c2] = (OUTT)v;
                }
            }
        }
    }
}

// ---------------- fused layer 1: one WAVE per node, all-register online softmax ----------------
__global__ __launch_bounds__(256)
void fused_l1(const int* __restrict__ ei, const int* __restrict__ off,
              const int* __restrict__ csr, const unsigned short* __restrict__ xl,
              const unsigned short* xr, const float* __restrict__ att,
              const float* __restrict__ bias, unsigned short* hout)
{
    const int lane = threadIdx.x & 63;
    const int n    = blockIdx.x * 4 + (threadIdx.x >> 6);
    if (n >= NODES) return;

    const int a = off[n], b = off[n + 1];

    const uint2 xrn = *(const uint2*)(xr + (size_t)n * C1 + lane * 4);
    const float xr0 = bf2f(xrn.x & 0xffff), xr1v = bf2f(xrn.x >> 16);
    const float xr2 = bf2f(xrn.y & 0xffff), xr3  = bf2f(xrn.y >> 16);
    const float4 wv = *(const float4*)(att + lane * 4);

    float m = -INFINITY, d = 0.f;
    float a0 = 0.f, a1 = 0.f, a2 = 0.f, a3 = 0.f;

    for (int base = a; base < b; base += 64) {
        const int cn = min(64, b - base);
        int mySrc = 0;
        if (lane < cn) {
            int e = csr[base + lane];
            mySrc = (e < NEDGE) ? ei[e] : (e - NEDGE);
        }

        #define ROW1(i) (*(const uint2*)(xl + (size_t)__shfl(mySrc, min((i), cn - 1)) * C1 + lane * 4))
        #define PROC1(i, R)                                                         \
        {                                                                           \
            const float x0 = bf2f((R).x & 0xffff), x1 = bf2f((R).x >> 16);          \
            const float x2 = bf2f((R).y & 0xffff), x3 = bf2f((R).y >> 16);          \
            float p = lrelu(x0 + xr0) * wv.x + lrelu(x1 + xr1v) * wv.y              \
                    + lrelu(x2 + xr2) * wv.z + lrelu(x3 + xr3) * wv.w;              \
            p += __shfl_xor(p, 1);                                                  \
            p += __shfl_xor(p, 2);                                                  \
            p += __shfl_xor(p, 4);                                                  \
            const float mN = fmaxf(m, p);                                           \
            const float sc = expf(m - mN);                                          \
            const float wg = expf(p - mN);                                          \
            m = mN;                                                                 \
            d = d * sc + wg;                                                        \
            a0 = a0 * sc + wg * x0;                                                 \
            a1 = a1 * sc + wg * x1;                                                 \
            a2 = a2 * sc + wg * x2;                                                 \
            a3 = a3 * sc + wg * x3;                                                 \
        }

        uint2 r0, r1, r2, r3;
        r0 = ROW1(0);
        if (1 < cn) r1 = ROW1(1);
        if (2 < cn) r2 = ROW1(2);
        if (3 < cn) r3 = ROW1(3);
        for (int i = 0; i < cn; i += 4) {
            PROC1(i, r0);
            if (i + 4 < cn) r0 = ROW1(i + 4);
            if (i + 1 < cn) {
                PROC1(i + 1, r1);
                if (i + 5 < cn) r1 = ROW1(i + 5);
            }
            if (i + 2 < cn) {
                PROC1(i + 2, r2);
                if (i + 6 < cn) r2 = ROW1(i + 6);
            }
            if (i + 3 < cn) {
                PROC1(i + 3, r3);
                if (i + 7 < cn) r3 = ROW1(i + 7);
            }
        }
        #undef ROW1
        #undef PROC1
    }

    const float inv = 1.f / d;
    const float4 bv = *(const float4*)(bias + lane * 4);
    float v0 = a0 * inv + bv.x, v1 = a1 * inv + bv.y;
    float v2 = a2 * inv + bv.z, v3 = a3 * inv + bv.w;
    v0 = v0 > 0.f ? v0 : (expf(v0) - 1.f);
    v1 = v1 > 0.f ? v1 : (expf(v1) - 1.f);
    v2 = v2 > 0.f ? v2 : (expf(v2) - 1.f);
    v3 = v3 > 0.f ? v3 : (expf(v3) - 1.f);
    uint2 o;
    o.x = (unsigned int)f2bf(v0) | ((unsigned int)f2bf(v1) << 16);
    o.y = (unsigned int)f2bf(v2) | ((unsigned int)f2bf(v3) << 16);
    *(uint2*)(hout + (size_t)n * C1 + lane * 4) = o;
}

// ---------------- fused layer 2: one WAVE per node + log_softmax ----------------
__global__ __launch_bounds__(256)
void fused_l2(const int* __restrict__ ei, const int* __restrict__ off,
              const int* __restrict__ csr, const float* __restrict__ h2l,
              const float* __restrict__ h2r, const float* __restrict__ att,
              const float* __restrict__ bias, float* __restrict__ out)
{
    const int lane = threadIdx.x & 63;
    const int n    = blockIdx.x * 4 + (threadIdx.x >> 6);
    if (n >= NODES) return;

    const int a = off[n], b = off[n + 1];
    const bool act = lane < C2;

    const float xrn = act ? h2r[(size_t)n * C2 + lane] : 0.f;
    const float av  = act ? att[lane] : 0.f;

    float m = -INFINITY, d = 0.f, acc = 0.f;

    for (int base = a; base < b; base += 64) {
        const int cn = min(64, b - base);
        int mySrc = 0;
        if (lane < cn) {
            int e = csr[base + lane];
            mySrc = (e < NEDGE) ? ei[e] : (e - NEDGE);
        }

        #define ROW2(i) (act ? h2l[(size_t)__shfl(mySrc, min((i), cn - 1)) * C2 + lane] : 0.f)
        #define PROC2(i, R)                                                         \
        {                                                                           \
            float p = lrelu((R) + xrn) * av;                                        \
            p += __shfl_xor(p, 1);                                                  \
            p += __shfl_xor(p, 2);                                                  \
            p += __shfl_xor(p, 4);                                                  \
            p += __shfl_xor(p, 8);                                                  \
            p += __shfl_xor(p, 16);                                                 \
            p += __shfl_xor(p, 32);                                                 \
            const float mN = fmaxf(m, p);                                           \
            const float sc = expf(m - mN);                                          \
            const float wg = expf(p - mN);                                          \
            m = mN;                                                                 \
            d = d * sc + wg;                                                        \
            acc = acc * sc + wg * (R);                                              \
        }

        float r0, r1, r2, r3;
        r0 = ROW2(0);
        if (1 < cn) r1 = ROW2(1);
        if (2 < cn) r2 = ROW2(2);
        if (3 < cn) r3 = ROW2(3);
        for (int i = 0; i < cn; i += 4) {
            PROC2(i, r0);
            if (i + 4 < cn) r0 = ROW2(i + 4);
            if (i + 1 < cn) {
                PROC2(i + 1, r1);
                if (i + 5 < cn) r1 = ROW2(i + 5);
            }
            if (i + 2 < cn) {
                PROC2(i + 2, r2);
                if (i + 6 < cn) r2 = ROW2(i + 6);
            }
            if (i + 3 < cn) {
                PROC2(i + 3, r3);
                if (i + 7 < cn) r3 = ROW2(i + 7);
            }
        }
        #undef ROW2
        #undef PROC2
    }

    float v = act ? (acc / d + bias[lane]) : -INFINITY;
    float mx = v;
    #pragma unroll
    for (int o = 32; o; o >>= 1) mx = fmaxf(mx, __shfl_xor(mx, o));
    float ex = act ? expf(v - mx) : 0.f;
    float s = ex;
    #pragma unroll
    for (int o = 32; o; o >>= 1) s += __shfl_xor(s, o);
    if (act) out[(size_t)n * C2 + lane] = v - mx - logf(s);
}

extern "C" void kernel_launch(void* const* d_in, const int* in_sizes, int n_in,
                              void* d_out, int out_size, void* d_ws, size_t ws_size,
                              hipStream_t stream)
{
    const float* x     = (const float*)d_in[0];
    const int*   ei    = (const int*)  d_in[1];
    const float* W1l   = (const float*)d_in[2];
    const float* b1l   = (const float*)d_in[3];
    const float* W1r   = (const float*)d_in[4];
    const float* b1r   = (const float*)d_in[5];
    const float* att1  = (const float*)d_in[6];
    const float* bias1 = (const float*)d_in[7];
    const float* W2l   = (const float*)d_in[8];
    const float* b2l   = (const float*)d_in[9];
    const float* W2r   = (const float*)d_in[10];
    const float* b2r   = (const float*)d_in[11];
    const float* att2  = (const float*)d_in[12];
    const float* bias2 = (const float*)d_in[13];
    float* out = (float*)d_out;

    float* ws = (float*)d_ws;
    unsigned short* xl1 = (unsigned short*)ws;               // 12.8M bf16 (25.6 MB)
    unsigned short* xr1 = (unsigned short*)(ws + 6400000);   // 12.8M bf16 (doubles as h)
    unsigned short* xb  = (unsigned short*)(ws + 12800000);  // x in bf16, 12.8M bf16
    int*   csr    = (int*)(ws + 19200000);                   // 450K
    int*   off    = csr + ETOT;                              // 50001
    int*   cnt    = off + (NODES + 1);
    int*   wrk    = cnt + NODES;
    int*   blkTot = wrk + NODES;
    int*   blkOff = blkTot + SCAN_NB;
    unsigned short* Wt1 = (unsigned short*)(ws + 19810000);  // 512*256 bf16
    unsigned short* Wt2 = (unsigned short*)(ws + 19880000);  // 80*256 bf16
    unsigned short* h = xr1;                                 // layer-1 output (in place)
    float* h2l = ws;                                         // 2M f32 (over dead xl1)
    float* h2r = ws + 2000000;

    const int* dstRow = ei + NEDGE;

    // ---- CSR build + input/weight prep ----
    zero_int<<<(NODES + 255) / 256, 256, 0, stream>>>(cnt, NODES);
    count_kernel<<<(ETOT + 255) / 256, 256, 0, stream>>>(dstRow, cnt);
    scan_blk<<<SCAN_NB, 256, 0, stream>>>(cnt, off, blkTot);
    scan_top<<<1, 256, 0, stream>>>(blkTot, blkOff, off + NODES);
    scan_fix<<<SCAN_NB, 256, 0, stream>>>(off, wrk, blkOff);
    place_kernel<<<(ETOT + 255) / 256, 256, 0, stream>>>(dstRow, wrk, csr);

    cvt_bf16<<<(NODES * DIN / 8 + 255) / 256, 256, 0, stream>>>(x, xb, NODES * DIN / 8);
    prep_w<<<(512 * 256 + 255) / 256, 256, 0, stream>>>(W1l, W1r, Wt1, DIN, C1);
    prep_w<<<(80 * 256 + 255) / 256, 256, 0, stream>>>(W2l, W2r, Wt2, C1, C2);

    // ---- layer 1 ----
    mfma_gemm<unsigned short><<<((NODES + GBM - 1) / GBM) * 4, 256, 0, stream>>>(
        xb, Wt1, b1l, b1r, xl1, xr1, NODES, DIN, 2 * C1, C1, 2);
    fused_l1<<<(NODES + 3) / 4, 256, 0, stream>>>(ei, off, csr, xl1, xr1, att1, bias1, h);

    // ---- layer 2 ----
    mfma_gemm<float><<<(NODES + GBM - 1) / GBM, 256, 0, stream>>>(
        h, Wt2, b2l, b2r, h2l, h2r, NODES, C1, 2 * C2, C2, 0);
    fused_l2<<<(NODES + 3) / 4, 256, 0, stream>>>(ei, off, csr, h2l, h2r, att2, bias2, out);
}

// Round 7
// 252.487 us; speedup vs baseline: 3.9265x; 1.0608x over previous
//
#include <hip/hip_runtime.h>
#include <math.h>

#define NODES 50000
#define NEDGE 400000
#define ETOT  450000   // NEDGE + NODES self loops
#define DIN   256
#define C1    256      // heads*dh = 8*32
#define C2    40
#define SCAN_NB ((NODES + 255) / 256)   // 196

typedef __attribute__((ext_vector_type(8))) short bfrag;
typedef __attribute__((ext_vector_type(4))) float facc;

#define GPTR(p) (const __attribute__((address_space(1))) unsigned int*)(p)
#define LPTR(p) (__attribute__((address_space(3))) unsigned int*)(p)

static __device__ __forceinline__ float bf2f(unsigned int u16) {
    unsigned int x = u16 << 16;
    float f;
    __builtin_memcpy(&f, &x, 4);
    return f;
}
static __device__ __forceinline__ float bitsf(unsigned int x) {
    float f;
    __builtin_memcpy(&f, &x, 4);
    return f;
}
static __device__ __forceinline__ unsigned short f2bf(float f) {
    unsigned int x;
    __builtin_memcpy(&x, &f, 4);
    unsigned int r = x + 0x7fffu + ((x >> 16) & 1u);   // RNE
    return (unsigned short)(r >> 16);
}
static __device__ __forceinline__ float fexp2(float x) {
#if __has_builtin(__builtin_amdgcn_exp2f)
    return __builtin_amdgcn_exp2f(x);
#else
    return exp2f(x);
#endif
}

// packed f32 (CDNA3/4 VOP3P): 2 f32 per instruction
static __device__ __forceinline__ float2 pk_fma(float2 a, float2 b, float2 c) {
    float2 d;
    asm("v_pk_fma_f32 %0, %1, %2, %3" : "=v"(d) : "v"(a), "v"(b), "v"(c));
    return d;
}
static __device__ __forceinline__ float2 pk_add(float2 a, float2 b) {
    float2 d;
    asm("v_pk_add_f32 %0, %1, %2" : "=v"(d) : "v"(a), "v"(b));
    return d;
}
static __device__ __forceinline__ float2 pk_mul(float2 a, float2 b) {
    float2 d;
    asm("v_pk_mul_f32 %0, %1, %2" : "=v"(d) : "v"(a), "v"(b));
    return d;
}

// ---------------- f32 -> bf16 bulk convert (8 elems/thread) ----------------
__global__ __launch_bounds__(256)
void cvt_bf16(const float* __restrict__ in, unsigned short* __restrict__ out, int n8) {
    int i = blockIdx.x * 256 + threadIdx.x;
    if (i >= n8) return;
    const float4* p = (const float4*)in + (size_t)i * 2;
    float4 u0 = p[0], u1 = p[1];
    bfrag pk;
    pk[0] = (short)f2bf(u0.x); pk[1] = (short)f2bf(u0.y);
    pk[2] = (short)f2bf(u0.z); pk[3] = (short)f2bf(u0.w);
    pk[4] = (short)f2bf(u1.x); pk[5] = (short)f2bf(u1.y);
    pk[6] = (short)f2bf(u1.z); pk[7] = (short)f2bf(u1.w);
    *(bfrag*)(out + (size_t)i * 8) = pk;
}

// ---------------- CSR build ----------------
__global__ void zero_int(int* p, int n) {
    int i = blockIdx.x * blockDim.x + threadIdx.x;
    if (i < n) p[i] = 0;
}

__global__ void count_kernel(const int* __restrict__ dstRow, int* __restrict__ cnt) {
    int e = blockIdx.x * blockDim.x + threadIdx.x;
    if (e >= ETOT) return;
    int d = (e < NEDGE) ? dstRow[e] : (e - NEDGE);
    atomicAdd(&cnt[d], 1);
}

// two-level parallel scan
__global__ __launch_bounds__(256)
void scan_blk(const int* __restrict__ cnt, int* __restrict__ off, int* __restrict__ blkTot) {
    __shared__ int buf[256];
    const int t = threadIdx.x;
    const int i = blockIdx.x * 256 + t;
    int v = (i < NODES) ? cnt[i] : 0;
    buf[t] = v;
    __syncthreads();
    #pragma unroll
    for (int d = 1; d < 256; d <<= 1) {
        int add = (t >= d) ? buf[t - d] : 0;
        __syncthreads();
        buf[t] += add;
        __syncthreads();
    }
    if (i < NODES) off[i] = buf[t] - v;   // local exclusive
    if (t == 255) blkTot[blockIdx.x] = buf[255];
}

__global__ __launch_bounds__(256)
void scan_top(const int* __restrict__ blkTot, int* __restrict__ blkOff, int* __restrict__ offEnd) {
    __shared__ int buf[256];
    const int t = threadIdx.x;
    int v = (t < SCAN_NB) ? blkTot[t] : 0;
    buf[t] = v;
    __syncthreads();
    #pragma unroll
    for (int d = 1; d < 256; d <<= 1) {
        int add = (t >= d) ? buf[t - d] : 0;
        __syncthreads();
        buf[t] += add;
        __syncthreads();
    }
    if (t < SCAN_NB) blkOff[t] = buf[t] - v;
    if (t == 255) *offEnd = buf[255];
}

__global__ __launch_bounds__(256)
void scan_fix(int* __restrict__ off, int* __restrict__ wrk, const int* __restrict__ blkOff) {
    const int i = blockIdx.x * 256 + threadIdx.x;
    if (i < NODES) {
        int v = off[i] + blkOff[blockIdx.x];
        off[i] = v;
        wrk[i] = v;
    }
}

__global__ void place_kernel(const int* __restrict__ dstRow, int* __restrict__ wrk,
                             int* __restrict__ csr) {
    int e = blockIdx.x * blockDim.x + threadIdx.x;
    if (e >= ETOT) return;
    int d = (e < NEDGE) ? dstRow[e] : (e - NEDGE);
    int slot = atomicAdd(&wrk[d], 1);
    csr[slot] = e;
}

// ---------------- weight transpose+cast: Wt[n][k] = bf16(W[k][n]) ----------------
__global__ void prep_w(const float* __restrict__ Wl, const float* __restrict__ Wr,
                       unsigned short* __restrict__ Wt, int K, int Nhalf) {
    int idx = blockIdx.x * 256 + threadIdx.x;   // n*K + k
    int n = idx / K;
    int k = idx - n * K;
    if (n >= 2 * Nhalf) return;
    float v = (n < Nhalf) ? Wl[(size_t)k * Nhalf + n] : Wr[(size_t)k * Nhalf + (n - Nhalf)];
    Wt[idx] = f2bf(v);
}

// ---------------- MFMA dual GEMM (bf16 A via global_load_lds) ----------------
#define GBM 128
#define GBN 128
#define GBK 32

template<typename OUTT>
__global__ __launch_bounds__(256)
void mfma_gemm(const unsigned short* __restrict__ Ab, const unsigned short* __restrict__ Bt,
               const float* __restrict__ bl, const float* __restrict__ br,
               OUTT* __restrict__ Cl, OUTT* __restrict__ Cr,
               int M, int K, int Nrows, int Nhalf, int nbnShift)
{
    __shared__ __align__(16) unsigned short As[GBM * GBK];
    __shared__ __align__(16) unsigned short Bs[GBN * GBK];

    const int tid  = threadIdx.x;
    const int lane = tid & 63;
    const int w    = tid >> 6;
    const int wr   = w >> 1;
    const int wc   = w & 1;
    const int bx   = blockIdx.x >> nbnShift;
    const int by   = blockIdx.x & ((1 << nbnShift) - 1);
    const int row0 = bx * GBM;
    const int col0 = by * GBN;

    facc acc[4][4];
    #pragma unroll
    for (int i = 0; i < 4; ++i)
        #pragma unroll
        for (int j = 0; j < 4; ++j) {
            facc z = {0.f, 0.f, 0.f, 0.f};
            acc[i][j] = z;
        }

    const int rA  = lane >> 2;
    const int sA  = lane & 3;
    const int kgA = sA ^ ((rA >> 1) & 3);

    for (int k0 = 0; k0 < K; k0 += GBK) {
        if (k0) __syncthreads();

        #pragma unroll
        for (int p = 0; p < 2; ++p) {
            int chunk = p * 4 + w;
            int r_loc = chunk * 16 + rA;
            int grow  = row0 + r_loc;
            if (grow < M)
                __builtin_amdgcn_global_load_lds(
                    GPTR(Ab + (size_t)grow * K + k0 + kgA * 8),
                    LPTR(As + chunk * 512), 16, 0, 0);
        }
        #pragma unroll
        for (int p = 0; p < 2; ++p) {
            int chunk = p * 4 + w;
            int r_loc = chunk * 16 + rA;
            int grow  = col0 + r_loc;
            if (grow < Nrows)
                __builtin_amdgcn_global_load_lds(
                    GPTR(Bt + (size_t)grow * K + k0 + kgA * 8),
                    LPTR(Bs + chunk * 512), 16, 0, 0);
        }

        __syncthreads();

        const int fr    = lane & 15;
        const int sRead = (lane >> 4) ^ ((fr >> 1) & 3);
        bfrag af[4], bfv[4];
        #pragma unroll
        for (int mi = 0; mi < 4; ++mi)
            af[mi] = *(const bfrag*)(As + (wr * 64 + mi * 16 + fr) * 32 + sRead * 8);
        #pragma unroll
        for (int ni = 0; ni < 4; ++ni)
            bfv[ni] = *(const bfrag*)(Bs + (wc * 64 + ni * 16 + fr) * 32 + sRead * 8);
        #pragma unroll
        for (int mi = 0; mi < 4; ++mi)
            #pragma unroll
            for (int ni = 0; ni < 4; ++ni)
                acc[mi][ni] = __builtin_amdgcn_mfma_f32_16x16x32_bf16(
                    af[mi], bfv[ni], acc[mi][ni], 0, 0, 0);
    }

    #pragma unroll
    for (int mi = 0; mi < 4; ++mi) {
        const int rbase = row0 + wr * 64 + mi * 16 + ((lane >> 4) << 2);
        #pragma unroll
        for (int ni = 0; ni < 4; ++ni) {
            const int col = col0 + wc * 64 + ni * 16 + (lane & 15);
            #pragma unroll
            for (int rg = 0; rg < 4; ++rg) {
                int r = rbase + rg;
                if (r >= M) continue;
                float v = acc[mi][ni][rg];
                if (col < Nhalf) {
                    v += bl[col];
                    if constexpr (sizeof(OUTT) == 2)
                        Cl[(size_t)r * Nhalf + col] = (OUTT)f2bf(v);
                    else
                        Cl[(size_t)r * Nhalf + col] = (OUTT)v;
                } else if (col < 2 * Nhalf) {
                    int c2 = col - Nhalf;
                    v += br[c2];
                    if constexpr (sizeof(OUTT) == 2)
                        Cr[(size_t)r * Nhalf + c2] = (OUTT)f2bf(v);
                    else
                        Cr[(size_t)r * Nhalf + c2] = (OUTT)v;
                }
            }
        }
    }
}

// ---------------- fused layer 1: one WAVE per node, exp2 + defer-max + pk f32 ----------------
__global__ __launch_bounds__(256)
void fused_l1(const int* __restrict__ ei, const int* __restrict__ off,
              const int* __restrict__ csr, const unsigned short* __restrict__ xl,
              const unsigned short* xr, const float* __restrict__ att,
              const float* __restrict__ bias, unsigned short* hout)
{
    const int lane = threadIdx.x & 63;
    const int n    = blockIdx.x * 4 + (threadIdx.x >> 6);
    if (n >= NODES) return;

    const int a = off[n], b = off[n + 1];

    const uint2 xrn = *(const uint2*)(xr + (size_t)n * C1 + lane * 4);
    const float2 xr01 = {bitsf(xrn.x << 16), bitsf(xrn.x & 0xffff0000u)};
    const float2 xr23 = {bitsf(xrn.y << 16), bitsf(xrn.y & 0xffff0000u)};
    const float4 wv = *(const float4*)(att + lane * 4);
    const float L2E = 1.4426950408889634f;
    const float2 w6_01 = {wv.x * (0.6f * L2E), wv.y * (0.6f * L2E)};
    const float2 w4_01 = {wv.x * (0.4f * L2E), wv.y * (0.4f * L2E)};
    const float2 w6_23 = {wv.z * (0.6f * L2E), wv.w * (0.6f * L2E)};
    const float2 w4_23 = {wv.z * (0.4f * L2E), wv.w * (0.4f * L2E)};

    float m = -INFINITY, d = 0.f;
    float2 ac01 = {0.f, 0.f}, ac23 = {0.f, 0.f};

    for (int base = a; base < b; base += 64) {
        const int cn = min(64, b - base);
        int mySrc = 0;
        if (lane < cn) {
            int e = csr[base + lane];
            mySrc = (e < NEDGE) ? ei[e] : (e - NEDGE);
        }

        #define ROW1(i) (*(const uint2*)(xl + (size_t)__shfl(mySrc, min((i), cn - 1)) * C1 + lane * 4))
        #define PROC1(i, R)                                                          \
        {                                                                            \
            const float2 x01 = {bitsf((R).x << 16), bitsf((R).x & 0xffff0000u)};     \
            const float2 x23 = {bitsf((R).y << 16), bitsf((R).y & 0xffff0000u)};     \
            const float2 v01 = pk_add(x01, xr01);                                    \
            const float2 v23 = pk_add(x23, xr23);                                    \
            const float2 av01 = {fabsf(v01.x), fabsf(v01.y)};                        \
            const float2 av23 = {fabsf(v23.x), fabsf(v23.y)};                        \
            float2 p2 = pk_mul(w6_01, v01);                                          \
            p2 = pk_fma(w4_01, av01, p2);                                            \
            p2 = pk_fma(w6_23, v23, p2);                                             \
            p2 = pk_fma(w4_23, av23, p2);                                            \
            float p = p2.x + p2.y;                                                   \
            p += __shfl_xor(p, 1);                                                   \
            p += __shfl_xor(p, 2);                                                   \
            p += __shfl_xor(p, 4);                                                   \
            if (__any(p > m + 8.f)) {                                                \
                const float mN = fmaxf(m, p);                                        \
                const float sc = fexp2(m - mN);                                      \
                const float wg = fexp2(p - mN);                                      \
                m = mN;                                                              \
                d = d * sc + wg;                                                     \
                const float2 s2 = {sc, sc};                                          \
                const float2 g2 = {wg, wg};                                          \
                ac01 = pk_fma(g2, x01, pk_mul(ac01, s2));                            \
                ac23 = pk_fma(g2, x23, pk_mul(ac23, s2));                            \
            } else {                                                                 \
                const float wg = fexp2(p - m);                                       \
                d += wg;                                                             \
                const float2 g2 = {wg, wg};                                          \
                ac01 = pk_fma(g2, x01, ac01);                                        \
                ac23 = pk_fma(g2, x23, ac23);                                        \
            }                                                                        \
        }

        uint2 r0, r1, r2, r3;
        r0 = ROW1(0);
        if (1 < cn) r1 = ROW1(1);
        if (2 < cn) r2 = ROW1(2);
        if (3 < cn) r3 = ROW1(3);
        for (int i = 0; i < cn; i += 4) {
            PROC1(i, r0);
            if (i + 4 < cn) r0 = ROW1(i + 4);
            if (i + 1 < cn) {
                PROC1(i + 1, r1);
                if (i + 5 < cn) r1 = ROW1(i + 5);
            }
            if (i + 2 < cn) {
                PROC1(i + 2, r2);
                if (i + 6 < cn) r2 = ROW1(i + 6);
            }
            if (i + 3 < cn) {
                PROC1(i + 3, r3);
                if (i + 7 < cn) r3 = ROW1(i + 7);
            }
        }
        #undef ROW1
        #undef PROC1
    }

    const float inv = 1.f / d;
    const float4 bv = *(const float4*)(bias + lane * 4);
    float v0 = ac01.x * inv + bv.x, v1 = ac01.y * inv + bv.y;
    float v2 = ac23.x * inv + bv.z, v3 = ac23.y * inv + bv.w;
    v0 = v0 > 0.f ? v0 : (expf(v0) - 1.f);
    v1 = v1 > 0.f ? v1 : (expf(v1) - 1.f);
    v2 = v2 > 0.f ? v2 : (expf(v2) - 1.f);
    v3 = v3 > 0.f ? v3 : (expf(v3) - 1.f);
    uint2 o;
    o.x = (unsigned int)f2bf(v0) | ((unsigned int)f2bf(v1) << 16);
    o.y = (unsigned int)f2bf(v2) | ((unsigned int)f2bf(v3) << 16);
    *(uint2*)(hout + (size_t)n * C1 + lane * 4) = o;
}

// ---------------- fused layer 2: one WAVE per node, exp2 + defer-max + log_softmax ----------------
__global__ __launch_bounds__(256)
void fused_l2(const int* __restrict__ ei, const int* __restrict__ off,
              const int* __restrict__ csr, const float* __restrict__ h2l,
              const float* __restrict__ h2r, const float* __restrict__ att,
              const float* __restrict__ bias, float* __restrict__ out)
{
    const int lane = threadIdx.x & 63;
    const int n    = blockIdx.x * 4 + (threadIdx.x >> 6);
    if (n >= NODES) return;

    const int a = off[n], b = off[n + 1];
    const bool act = lane < C2;

    const float L2E = 1.4426950408889634f;
    const float xrn = act ? h2r[(size_t)n * C2 + lane] : 0.f;
    const float w   = act ? att[lane] : 0.f;
    const float w6 = w * (0.6f * L2E), w4 = w * (0.4f * L2E);

    float m = -INFINITY, d = 0.f, acc = 0.f;

    for (int base = a; base < b; base += 64) {
        const int cn = min(64, b - base);
        int mySrc = 0;
        if (lane < cn) {
            int e = csr[base + lane];
            mySrc = (e < NEDGE) ? ei[e] : (e - NEDGE);
        }

        #define ROW2(i) (act ? h2l[(size_t)__shfl(mySrc, min((i), cn - 1)) * C2 + lane] : 0.f)
        #define PROC2(i, R)                                                         \
        {                                                                           \
            const float v = (R) + xrn;                                              \
            float p = w6 * v + w4 * fabsf(v);                                       \
            p += __shfl_xor(p, 1);                                                  \
            p += __shfl_xor(p, 2);                                                  \
            p += __shfl_xor(p, 4);                                                  \
            p += __shfl_xor(p, 8);                                                  \
            p += __shfl_xor(p, 16);                                                 \
            p += __shfl_xor(p, 32);                                                 \
            if (__any(p > m + 8.f)) {                                               \
                const float mN = fmaxf(m, p);                                       \
                const float sc = fexp2(m - mN);                                     \
                const float wg = fexp2(p - mN);                                     \
                m = mN;                                                             \
                d = d * sc + wg;                                                    \
                acc = acc * sc + wg * (R);                                          \
            } else {                                                                \
                const float wg = fexp2(p - m);                                      \
                d += wg;                                                            \
                acc = fmaf(wg, (R), acc);                                           \
            }                                                                       \
        }

        float r0, r1, r2, r3;
        r0 = ROW2(0);
        if (1 < cn) r1 = ROW2(1);
        if (2 < cn) r2 = ROW2(2);
        if (3 < cn) r3 = ROW2(3);
        for (int i = 0; i < cn; i += 4) {
            PROC2(i, r0);
            if (i + 4 < cn) r0 = ROW2(i + 4);
            if (i + 1 < cn) {
                PROC2(i + 1, r1);
                if (i + 5 < cn) r1 = ROW2(i + 5);
            }
            if (i + 2 < cn) {
                PROC2(i + 2, r2);
                if (i + 6 < cn) r2 = ROW2(i + 6);
            }
            if (i + 3 < cn) {
                PROC2(i + 3, r3);
                if (i + 7 < cn) r3 = ROW2(i + 7);
            }
        }
        #undef ROW2
        #undef PROC2
    }

    float v = act ? (acc / d + bias[lane]) : -INFINITY;
    float mx = v;
    #pragma unroll
    for (int o = 32; o; o >>= 1) mx = fmaxf(mx, __shfl_xor(mx, o));
    float ex = act ? expf(v - mx) : 0.f;
    float s = ex;
    #pragma unroll
    for (int o = 32; o; o >>= 1) s += __shfl_xor(s, o);
    if (act) out[(size_t)n * C2 + lane] = v - mx - logf(s);
}

extern "C" void kernel_launch(void* const* d_in, const int* in_sizes, int n_in,
                              void* d_out, int out_size, void* d_ws, size_t ws_size,
                              hipStream_t stream)
{
    const float* x     = (const float*)d_in[0];
    const int*   ei    = (const int*)  d_in[1];
    const float* W1l   = (const float*)d_in[2];
    const float* b1l   = (const float*)d_in[3];
    const float* W1r   = (const float*)d_in[4];
    const float* b1r   = (const float*)d_in[5];
    const float* att1  = (const float*)d_in[6];
    const float* bias1 = (const float*)d_in[7];
    const float* W2l   = (const float*)d_in[8];
    const float* b2l   = (const float*)d_in[9];
    const float* W2r   = (const float*)d_in[10];
    const float* b2r   = (const float*)d_in[11];
    const float* att2  = (const float*)d_in[12];
    const float* bias2 = (const float*)d_in[13];
    float* out = (float*)d_out;

    float* ws = (float*)d_ws;
    unsigned short* xl1 = (unsigned short*)ws;               // 12.8M bf16 (25.6 MB)
    unsigned short* xr1 = (unsigned short*)(ws + 6400000);   // 12.8M bf16 (doubles as h)
    unsigned short* xb  = (unsigned short*)(ws + 12800000);  // x in bf16, 12.8M bf16
    int*   csr    = (int*)(ws + 19200000);                   // 450K
    int*   off    = csr + ETOT;                              // 50001
    int*   cnt    = off + (NODES + 1);
    int*   wrk    = cnt + NODES;
    int*   blkTot = wrk + NODES;
    int*   blkOff = blkTot + SCAN_NB;
    unsigned short* Wt1 = (unsigned short*)(ws + 19810000);  // 512*256 bf16
    unsigned short* Wt2 = (unsigned short*)(ws + 19880000);  // 80*256 bf16
    unsigned short* h = xr1;                                 // layer-1 output (in place)
    float* h2l = ws;                                         // 2M f32 (over dead xl1)
    float* h2r = ws + 2000000;

    const int* dstRow = ei + NEDGE;

    // ---- CSR build + input/weight prep ----
    zero_int<<<(NODES + 255) / 256, 256, 0, stream>>>(cnt, NODES);
    count_kernel<<<(ETOT + 255) / 256, 256, 0, stream>>>(dstRow, cnt);
    scan_blk<<<SCAN_NB, 256, 0, stream>>>(cnt, off, blkTot);
    scan_top<<<1, 256, 0, stream>>>(blkTot, blkOff, off + NODES);
    scan_fix<<<SCAN_NB, 256, 0, stream>>>(off, wrk, blkOff);
    place_kernel<<<(ETOT + 255) / 256, 256, 0, stream>>>(dstRow, wrk, csr);

    cvt_bf16<<<(NODES * DIN / 8 + 255) / 256, 256, 0, stream>>>(x, xb, NODES * DIN / 8);
    prep_w<<<(512 * 256 + 255) / 256, 256, 0, stream>>>(W1l, W1r, Wt1, DIN, C1);
    prep_w<<<(80 * 256 + 255) / 256, 256, 0, stream>>>(W2l, W2r, Wt2, C1, C2);

    // ---- layer 1 ----
    mfma_gemm<unsigned short><<<((NODES + GBM - 1) / GBM) * 4, 256, 0, stream>>>(
        xb, Wt1, b1l, b1r, xl1, xr1, NODES, DIN, 2 * C1, C1, 2);
    fused_l1<<<(NODES + 3) / 4, 256, 0, stream>>>(ei, off, csr, xl1, xr1, att1, bias1, h);

    // ---- layer 2 ----
    mfma_gemm<float><<<(NODES + GBM - 1) / GBM, 256, 0, stream>>>(
        h, Wt2, b2l, b2r, h2l, h2r, NODES, C1, 2 * C2, C2, 0);
    fused_l2<<<(NODES + 3) / 4, 256, 0, stream>>>(ei, off, csr, h2l, h2r, att2, bias2, out);
}

// Round 8
// 221.649 us; speedup vs baseline: 4.4728x; 1.1391x over previous
//
#include <hip/hip_runtime.h>
#include <math.h>

#define NODES 50000
#define NEDGE 400000
#define ETOT  450000   // NEDGE + NODES self loops
#define DIN   256
#define C1    256      // heads*dh = 8*32
#define C2    40
#define SCAN_NB ((NODES + 255) / 256)   // 196

typedef __attribute__((ext_vector_type(8))) short bfrag;
typedef __attribute__((ext_vector_type(4))) float facc;

#define GPTR(p) (const __attribute__((address_space(1))) unsigned int*)(p)
#define LPTR(p) (__attribute__((address_space(3))) unsigned int*)(p)

static __device__ __forceinline__ float bf2f(unsigned int u16) {
    unsigned int x = u16 << 16;
    float f;
    __builtin_memcpy(&f, &x, 4);
    return f;
}
static __device__ __forceinline__ float bitsf(unsigned int x) {
    float f;
    __builtin_memcpy(&f, &x, 4);
    return f;
}
static __device__ __forceinline__ unsigned short f2bf(float f) {
    unsigned int x;
    __builtin_memcpy(&x, &f, 4);
    unsigned int r = x + 0x7fffu + ((x >> 16) & 1u);   // RNE
    return (unsigned short)(r >> 16);
}
static __device__ __forceinline__ float fexp2(float x) {
#if __has_builtin(__builtin_amdgcn_exp2f)
    return __builtin_amdgcn_exp2f(x);
#else
    return exp2f(x);
#endif
}

// packed f32 (CDNA3/4 VOP3P): 2 f32 per instruction
static __device__ __forceinline__ float2 pk_fma(float2 a, float2 b, float2 c) {
    float2 d;
    asm("v_pk_fma_f32 %0, %1, %2, %3" : "=v"(d) : "v"(a), "v"(b), "v"(c));
    return d;
}
static __device__ __forceinline__ float2 pk_add(float2 a, float2 b) {
    float2 d;
    asm("v_pk_add_f32 %0, %1, %2" : "=v"(d) : "v"(a), "v"(b));
    return d;
}
static __device__ __forceinline__ float2 pk_mul(float2 a, float2 b) {
    float2 d;
    asm("v_pk_mul_f32 %0, %1, %2" : "=v"(d) : "v"(a), "v"(b));
    return d;
}

// ---------------- f32 -> bf16 bulk convert (8 elems/thread) ----------------
__global__ __launch_bounds__(256)
void cvt_bf16(const float* __restrict__ in, unsigned short* __restrict__ out, int n8) {
    int i = blockIdx.x * 256 + threadIdx.x;
    if (i >= n8) return;
    const float4* p = (const float4*)in + (size_t)i * 2;
    float4 u0 = p[0], u1 = p[1];
    bfrag pk;
    pk[0] = (short)f2bf(u0.x); pk[1] = (short)f2bf(u0.y);
    pk[2] = (short)f2bf(u0.z); pk[3] = (short)f2bf(u0.w);
    pk[4] = (short)f2bf(u1.x); pk[5] = (short)f2bf(u1.y);
    pk[6] = (short)f2bf(u1.z); pk[7] = (short)f2bf(u1.w);
    *(bfrag*)(out + (size_t)i * 8) = pk;
}

// ---------------- CSR build ----------------
__global__ void zero_int(int* p, int n) {
    int i = blockIdx.x * blockDim.x + threadIdx.x;
    if (i < n) p[i] = 0;
}

__global__ void count_kernel(const int* __restrict__ dstRow, int* __restrict__ cnt) {
    int e = blockIdx.x * blockDim.x + threadIdx.x;
    if (e >= ETOT) return;
    int d = (e < NEDGE) ? dstRow[e] : (e - NEDGE);
    atomicAdd(&cnt[d], 1);
}

// two-level parallel scan
__global__ __launch_bounds__(256)
void scan_blk(const int* __restrict__ cnt, int* __restrict__ off, int* __restrict__ blkTot) {
    __shared__ int buf[256];
    const int t = threadIdx.x;
    const int i = blockIdx.x * 256 + t;
    int v = (i < NODES) ? cnt[i] : 0;
    buf[t] = v;
    __syncthreads();
    #pragma unroll
    for (int d = 1; d < 256; d <<= 1) {
        int add = (t >= d) ? buf[t - d] : 0;
        __syncthreads();
        buf[t] += add;
        __syncthreads();
    }
    if (i < NODES) off[i] = buf[t] - v;   // local exclusive
    if (t == 255) blkTot[blockIdx.x] = buf[255];
}

__global__ __launch_bounds__(256)
void scan_top(const int* __restrict__ blkTot, int* __restrict__ blkOff, int* __restrict__ offEnd) {
    __shared__ int buf[256];
    const int t = threadIdx.x;
    int v = (t < SCAN_NB) ? blkTot[t] : 0;
    buf[t] = v;
    __syncthreads();
    #pragma unroll
    for (int d = 1; d < 256; d <<= 1) {
        int add = (t >= d) ? buf[t - d] : 0;
        __syncthreads();
        buf[t] += add;
        __syncthreads();
    }
    if (t < SCAN_NB) blkOff[t] = buf[t] - v;
    if (t == 255) *offEnd = buf[255];
}

__global__ __launch_bounds__(256)
void scan_fix(int* __restrict__ off, int* __restrict__ wrk, const int* __restrict__ blkOff) {
    const int i = blockIdx.x * 256 + threadIdx.x;
    if (i < NODES) {
        int v = off[i] + blkOff[blockIdx.x];
        off[i] = v;
        wrk[i] = v;
    }
}

// store SOURCE NODE directly in csr (kills one dependent load in the fused kernels)
__global__ void place_kernel(const int* __restrict__ srcRow, const int* __restrict__ dstRow,
                             int* __restrict__ wrk, int* __restrict__ csr) {
    int e = blockIdx.x * blockDim.x + threadIdx.x;
    if (e >= ETOT) return;
    int d, s;
    if (e < NEDGE) { d = dstRow[e]; s = srcRow[e]; }
    else           { d = e - NEDGE; s = d; }
    int slot = atomicAdd(&wrk[d], 1);
    csr[slot] = s;
}

// ---------------- weight transpose+cast: Wt[n][k] = bf16(W[k][n]) ----------------
__global__ void prep_w(const float* __restrict__ Wl, const float* __restrict__ Wr,
                       unsigned short* __restrict__ Wt, int K, int Nhalf) {
    int idx = blockIdx.x * 256 + threadIdx.x;   // n*K + k
    int n = idx / K;
    int k = idx - n * K;
    if (n >= 2 * Nhalf) return;
    float v = (n < Nhalf) ? Wl[(size_t)k * Nhalf + n] : Wr[(size_t)k * Nhalf + (n - Nhalf)];
    Wt[idx] = f2bf(v);
}

// ---------------- MFMA dual GEMM (bf16 A via global_load_lds) ----------------
#define GBM 128
#define GBN 128
#define GBK 32

template<typename OUTT>
__global__ __launch_bounds__(256)
void mfma_gemm(const unsigned short* __restrict__ Ab, const unsigned short* __restrict__ Bt,
               const float* __restrict__ bl, const float* __restrict__ br,
               OUTT* __restrict__ Cl, OUTT* __restrict__ Cr,
               int M, int K, int Nrows, int Nhalf, int nbnShift)
{
    __shared__ __align__(16) unsigned short As[GBM * GBK];
    __shared__ __align__(16) unsigned short Bs[GBN * GBK];

    const int tid  = threadIdx.x;
    const int lane = tid & 63;
    const int w    = tid >> 6;
    const int wr   = w >> 1;
    const int wc   = w & 1;
    const int bx   = blockIdx.x >> nbnShift;
    const int by   = blockIdx.x & ((1 << nbnShift) - 1);
    const int row0 = bx * GBM;
    const int col0 = by * GBN;

    facc acc[4][4];
    #pragma unroll
    for (int i = 0; i < 4; ++i)
        #pragma unroll
        for (int j = 0; j < 4; ++j) {
            facc z = {0.f, 0.f, 0.f, 0.f};
            acc[i][j] = z;
        }

    const int rA  = lane >> 2;
    const int sA  = lane & 3;
    const int kgA = sA ^ ((rA >> 1) & 3);

    for (int k0 = 0; k0 < K; k0 += GBK) {
        if (k0) __syncthreads();

        #pragma unroll
        for (int p = 0; p < 2; ++p) {
            int chunk = p * 4 + w;
            int r_loc = chunk * 16 + rA;
            int grow  = row0 + r_loc;
            if (grow < M)
                __builtin_amdgcn_global_load_lds(
                    GPTR(Ab + (size_t)grow * K + k0 + kgA * 8),
                    LPTR(As + chunk * 512), 16, 0, 0);
        }
        #pragma unroll
        for (int p = 0; p < 2; ++p) {
            int chunk = p * 4 + w;
            int r_loc = chunk * 16 + rA;
            int grow  = col0 + r_loc;
            if (grow < Nrows)
                __builtin_amdgcn_global_load_lds(
                    GPTR(Bt + (size_t)grow * K + k0 + kgA * 8),
                    LPTR(Bs + chunk * 512), 16, 0, 0);
        }

        __syncthreads();

        const int fr    = lane & 15;
        const int sRead = (lane >> 4) ^ ((fr >> 1) & 3);
        bfrag af[4], bfv[4];
        #pragma unroll
        for (int mi = 0; mi < 4; ++mi)
            af[mi] = *(const bfrag*)(As + (wr * 64 + mi * 16 + fr) * 32 + sRead * 8);
        #pragma unroll
        for (int ni = 0; ni < 4; ++ni)
            bfv[ni] = *(const bfrag*)(Bs + (wc * 64 + ni * 16 + fr) * 32 + sRead * 8);
        #pragma unroll
        for (int mi = 0; mi < 4; ++mi)
            #pragma unroll
            for (int ni = 0; ni < 4; ++ni)
                acc[mi][ni] = __builtin_amdgcn_mfma_f32_16x16x32_bf16(
                    af[mi], bfv[ni], acc[mi][ni], 0, 0, 0);
    }

    #pragma unroll
    for (int mi = 0; mi < 4; ++mi) {
        const int rbase = row0 + wr * 64 + mi * 16 + ((lane >> 4) << 2);
        #pragma unroll
        for (int ni = 0; ni < 4; ++ni) {
            const int col = col0 + wc * 64 + ni * 16 + (lane & 15);
            #pragma unroll
            for (int rg = 0; rg < 4; ++rg) {
                int r = rbase + rg;
                if (r >= M) continue;
                float v = acc[mi][ni][rg];
                if (col < Nhalf) {
                    v += bl[col];
                    if constexpr (sizeof(OUTT) == 2)
                        Cl[(size_t)r * Nhalf + col] = (OUTT)f2bf(v);
                    else
                        Cl[(size_t)r * Nhalf + col] = (OUTT)v;
                } else if (col < 2 * Nhalf) {
                    int c2 = col - Nhalf;
                    v += br[c2];
                    if constexpr (sizeof(OUTT) == 2)
                        Cr[(size_t)r * Nhalf + c2] = (OUTT)f2bf(v);
                    else
                        Cr[(size_t)r * Nhalf + c2] = (OUTT)v;
                }
            }
        }
    }
}

// ---------------- fused layer 1: one WAVE per node, exp2 + defer-max + pk f32 ----------------
__global__ __launch_bounds__(256)
void fused_l1(const int* __restrict__ off,
              const int* __restrict__ csr, const unsigned short* __restrict__ xl,
              const unsigned short* xr, const float* __restrict__ att,
              const float* __restrict__ bias, unsigned short* hout)
{
    const int lane = threadIdx.x & 63;
    const int n    = blockIdx.x * 4 + (threadIdx.x >> 6);
    if (n >= NODES) return;

    const int a = off[n], b = off[n + 1];

    const uint2 xrn = *(const uint2*)(xr + (size_t)n * C1 + lane * 4);
    const float2 xr01 = {bitsf(xrn.x << 16), bitsf(xrn.x & 0xffff0000u)};
    const float2 xr23 = {bitsf(xrn.y << 16), bitsf(xrn.y & 0xffff0000u)};
    const float4 wv = *(const float4*)(att + lane * 4);
    const float L2E = 1.4426950408889634f;
    const float2 w6_01 = {wv.x * (0.6f * L2E), wv.y * (0.6f * L2E)};
    const float2 w4_01 = {wv.x * (0.4f * L2E), wv.y * (0.4f * L2E)};
    const float2 w6_23 = {wv.z * (0.6f * L2E), wv.w * (0.6f * L2E)};
    const float2 w4_23 = {wv.z * (0.4f * L2E), wv.w * (0.4f * L2E)};

    float m = -INFINITY, d = 0.f;
    float2 ac01 = {0.f, 0.f}, ac23 = {0.f, 0.f};

    for (int base = a; base < b; base += 64) {
        const int cn = min(64, b - base);
        int mySrc = 0;
        if (lane < cn) mySrc = csr[base + lane];   // src stored directly

        #define ROW1(i) (*(const uint2*)(xl + (size_t)__shfl(mySrc, min((i), cn - 1)) * C1 + lane * 4))
        #define PROC1(i, R)                                                          \
        {                                                                            \
            const float2 x01 = {bitsf((R).x << 16), bitsf((R).x & 0xffff0000u)};     \
            const float2 x23 = {bitsf((R).y << 16), bitsf((R).y & 0xffff0000u)};     \
            const float2 v01 = pk_add(x01, xr01);                                    \
            const float2 v23 = pk_add(x23, xr23);                                    \
            const float2 av01 = {fabsf(v01.x), fabsf(v01.y)};                        \
            const float2 av23 = {fabsf(v23.x), fabsf(v23.y)};                        \
            float2 p2 = pk_mul(w6_01, v01);                                          \
            p2 = pk_fma(w4_01, av01, p2);                                            \
            p2 = pk_fma(w6_23, v23, p2);                                             \
            p2 = pk_fma(w4_23, av23, p2);                                            \
            float p = p2.x + p2.y;                                                   \
            p += __shfl_xor(p, 1);                                                   \
            p += __shfl_xor(p, 2);                                                   \
            p += __shfl_xor(p, 4);                                                   \
            if (__any(p > m + 8.f)) {                                                \
                const float mN = fmaxf(m, p);                                        \
                const float sc = fexp2(m - mN);                                      \
                const float wg = fexp2(p - mN);                                      \
                m = mN;                                                              \
                d = d * sc + wg;                                                     \
                const float2 s2 = {sc, sc};                                          \
                const float2 g2 = {wg, wg};                                          \
                ac01 = pk_fma(g2, x01, pk_mul(ac01, s2));                            \
                ac23 = pk_fma(g2, x23, pk_mul(ac23, s2));                            \
            } else {                                                                 \
                const float wg = fexp2(p - m);                                       \
                d += wg;                                                             \
                const float2 g2 = {wg, wg};                                          \
                ac01 = pk_fma(g2, x01, ac01);                                        \
                ac23 = pk_fma(g2, x23, ac23);                                        \
            }                                                                        \
        }

        uint2 r0, r1, r2, r3;
        r0 = ROW1(0);
        if (1 < cn) r1 = ROW1(1);
        if (2 < cn) r2 = ROW1(2);
        if (3 < cn) r3 = ROW1(3);
        for (int i = 0; i < cn; i += 4) {
            PROC1(i, r0);
            if (i + 4 < cn) r0 = ROW1(i + 4);
            if (i + 1 < cn) {
                PROC1(i + 1, r1);
                if (i + 5 < cn) r1 = ROW1(i + 5);
            }
            if (i + 2 < cn) {
                PROC1(i + 2, r2);
                if (i + 6 < cn) r2 = ROW1(i + 6);
            }
            if (i + 3 < cn) {
                PROC1(i + 3, r3);
                if (i + 7 < cn) r3 = ROW1(i + 7);
            }
        }
        #undef ROW1
        #undef PROC1
    }

    const float inv = 1.f / d;
    const float4 bv = *(const float4*)(bias + lane * 4);
    float v0 = ac01.x * inv + bv.x, v1 = ac01.y * inv + bv.y;
    float v2 = ac23.x * inv + bv.z, v3 = ac23.y * inv + bv.w;
    v0 = v0 > 0.f ? v0 : (expf(v0) - 1.f);
    v1 = v1 > 0.f ? v1 : (expf(v1) - 1.f);
    v2 = v2 > 0.f ? v2 : (expf(v2) - 1.f);
    v3 = v3 > 0.f ? v3 : (expf(v3) - 1.f);
    uint2 o;
    o.x = (unsigned int)f2bf(v0) | ((unsigned int)f2bf(v1) << 16);
    o.y = (unsigned int)f2bf(v2) | ((unsigned int)f2bf(v3) << 16);
    *(uint2*)(hout + (size_t)n * C1 + lane * 4) = o;
}

// ---------------- fused layer 2: 8-edge-parallel groups + log_softmax ----------------
// wave = 8 groups x 8 lanes; group g handles edge chunk+g; lane owns 5 channels (stride 8)
__global__ __launch_bounds__(256)
void fused_l2(const int* __restrict__ off,
              const int* __restrict__ csr, const float* __restrict__ h2l,
              const float* __restrict__ h2r, const float* __restrict__ att,
              const float* __restrict__ bias, float* __restrict__ out)
{
    const int lane = threadIdx.x & 63;
    const int n    = blockIdx.x * 4 + (threadIdx.x >> 6);
    if (n >= NODES) return;
    const int l8 = lane & 7;    // channel sub-index
    const int g  = lane >> 3;   // edge group

    const int a = off[n], b = off[n + 1];
    const float L2E = 1.4426950408889634f;

    float w6[5], w4[5], xr[5];
    #pragma unroll
    for (int j = 0; j < 5; ++j) {
        const int c = l8 + 8 * j;
        const float w = att[c];
        w6[j] = w * (0.6f * L2E);
        w4[j] = w * (0.4f * L2E);
        xr[j] = h2r[(size_t)n * C2 + c];
    }

    float m = -INFINITY, dl = 0.f;
    float acc[5] = {0.f, 0.f, 0.f, 0.f, 0.f};

    for (int base = a; base < b; base += 64) {
        const int cn = min(64, b - base);
        int mySrc = 0;
        if (lane < cn) mySrc = csr[base + lane];   // src stored directly

        for (int c0 = 0; c0 < cn; c0 += 8) {
            const int idx = c0 + g;
            const bool active = idx < cn;
            const int src = __shfl(mySrc, min(idx, cn - 1));
            const float* row = h2l + (size_t)src * C2 + l8;
            float R[5];
            #pragma unroll
            for (int j = 0; j < 5; ++j) R[j] = row[8 * j];

            float p = 0.f;
            #pragma unroll
            for (int j = 0; j < 5; ++j) {
                const float v = R[j] + xr[j];
                p = fmaf(w6[j], v, p);
                p = fmaf(w4[j], fabsf(v), p);
            }
            p += __shfl_xor(p, 1);
            p += __shfl_xor(p, 2);
            p += __shfl_xor(p, 4);
            if (!active) p = -INFINITY;

            if (__any(p > m + 8.f)) {
                float pm = p;
                pm = fmaxf(pm, __shfl_xor(pm, 8));
                pm = fmaxf(pm, __shfl_xor(pm, 16));
                pm = fmaxf(pm, __shfl_xor(pm, 32));
                const float mN = fmaxf(m, pm);
                const float sc = fexp2(m - mN);
                const float wg = fexp2(p - mN);
                m = mN;
                dl = dl * sc + wg;
                #pragma unroll
                for (int j = 0; j < 5; ++j) acc[j] = fmaf(wg, R[j], acc[j] * sc);
            } else {
                const float wg = fexp2(p - m);
                dl += wg;
                #pragma unroll
                for (int j = 0; j < 5; ++j) acc[j] = fmaf(wg, R[j], acc[j]);
            }
        }
    }

    // cross-group butterfly reductions (d and acc)
    #pragma unroll
    for (int o = 8; o < 64; o <<= 1) {
        dl += __shfl_xor(dl, o);
        #pragma unroll
        for (int j = 0; j < 5; ++j) acc[j] += __shfl_xor(acc[j], o);
    }

    const float inv = 1.f / dl;
    float v[5];
    float mx = -INFINITY;
    #pragma unroll
    for (int j = 0; j < 5; ++j) {
        v[j] = acc[j] * inv + bias[l8 + 8 * j];
        mx = fmaxf(mx, v[j]);
    }
    mx = fmaxf(mx, __shfl_xor(mx, 1));
    mx = fmaxf(mx, __shfl_xor(mx, 2));
    mx = fmaxf(mx, __shfl_xor(mx, 4));
    float s = 0.f;
    #pragma unroll
    for (int j = 0; j < 5; ++j) s += expf(v[j] - mx);
    s += __shfl_xor(s, 1);
    s += __shfl_xor(s, 2);
    s += __shfl_xor(s, 4);
    const float lg = logf(s);
    if (g == 0) {
        #pragma unroll
        for (int j = 0; j < 5; ++j)
            out[(size_t)n * C2 + l8 + 8 * j] = v[j] - mx - lg;
    }
}

extern "C" void kernel_launch(void* const* d_in, const int* in_sizes, int n_in,
                              void* d_out, int out_size, void* d_ws, size_t ws_size,
                              hipStream_t stream)
{
    const float* x     = (const float*)d_in[0];
    const int*   ei    = (const int*)  d_in[1];
    const float* W1l   = (const float*)d_in[2];
    const float* b1l   = (const float*)d_in[3];
    const float* W1r   = (const float*)d_in[4];
    const float* b1r   = (const float*)d_in[5];
    const float* att1  = (const float*)d_in[6];
    const float* bias1 = (const float*)d_in[7];
    const float* W2l   = (const float*)d_in[8];
    const float* b2l   = (const float*)d_in[9];
    const float* W2r   = (const float*)d_in[10];
    const float* b2r   = (const float*)d_in[11];
    const float* att2  = (const float*)d_in[12];
    const float* bias2 = (const float*)d_in[13];
    float* out = (float*)d_out;

    float* ws = (float*)d_ws;
    unsigned short* xl1 = (unsigned short*)ws;               // 12.8M bf16 (25.6 MB)
    unsigned short* xr1 = (unsigned short*)(ws + 6400000);   // 12.8M bf16 (doubles as h)
    unsigned short* xb  = (unsigned short*)(ws + 12800000);  // x in bf16, 12.8M bf16
    int*   csr    = (int*)(ws + 19200000);                   // 450K
    int*   off    = csr + ETOT;                              // 50001
    int*   cnt    = off + (NODES + 1);
    int*   wrk    = cnt + NODES;
    int*   blkTot = wrk + NODES;
    int*   blkOff = blkTot + SCAN_NB;
    unsigned short* Wt1 = (unsigned short*)(ws + 19810000);  // 512*256 bf16
    unsigned short* Wt2 = (unsigned short*)(ws + 19880000);  // 80*256 bf16
    unsigned short* h = xr1;                                 // layer-1 output (in place)
    float* h2l = ws;                                         // 2M f32 (over dead xl1)
    float* h2r = ws + 2000000;

    const int* srcRow = ei;
    const int* dstRow = ei + NEDGE;

    // ---- CSR build + input/weight prep ----
    zero_int<<<(NODES + 255) / 256, 256, 0, stream>>>(cnt, NODES);
    count_kernel<<<(ETOT + 255) / 256, 256, 0, stream>>>(dstRow, cnt);
    scan_blk<<<SCAN_NB, 256, 0, stream>>>(cnt, off, blkTot);
    scan_top<<<1, 256, 0, stream>>>(blkTot, blkOff, off + NODES);
    scan_fix<<<SCAN_NB, 256, 0, stream>>>(off, wrk, blkOff);
    place_kernel<<<(ETOT + 255) / 256, 256, 0, stream>>>(srcRow, dstRow, wrk, csr);

    cvt_bf16<<<(NODES * DIN / 8 + 255) / 256, 256, 0, stream>>>(x, xb, NODES * DIN / 8);
    prep_w<<<(512 * 256 + 255) / 256, 256, 0, stream>>>(W1l, W1r, Wt1, DIN, C1);
    prep_w<<<(80 * 256 + 255) / 256, 256, 0, stream>>>(W2l, W2r, Wt2, C1, C2);

    // ---- layer 1 ----
    mfma_gemm<unsigned short><<<((NODES + GBM - 1) / GBM) * 4, 256, 0, stream>>>(
        xb, Wt1, b1l, b1r, xl1, xr1, NODES, DIN, 2 * C1, C1, 2);
    fused_l1<<<(NODES + 3) / 4, 256, 0, stream>>>(off, csr, xl1, xr1, att1, bias1, h);

    // ---- layer 2 ----
    mfma_gemm<float><<<(NODES + GBM - 1) / GBM, 256, 0, stream>>>(
        h, Wt2, b2l, b2r, h2l, h2r, NODES, C1, 2 * C2, C2, 0);
    fused_l2<<<(NODES + 3) / 4, 256, 0, stream>>>(off, csr, h2l, h2r, att2, bias2, out);
}

// Round 9
// 215.322 us; speedup vs baseline: 4.6042x; 1.0294x over previous
//
#include <hip/hip_runtime.h>
#include <math.h>

#define NODES 50000
#define NEDGE 400000
#define ETOT  450000   // NEDGE + NODES self loops
#define DIN   256
#define C1    256      // heads*dh = 8*32
#define C2    40
#define SCAN_NB ((NODES + 255) / 256)   // 196

typedef __attribute__((ext_vector_type(8))) short bfrag;
typedef __attribute__((ext_vector_type(4))) float facc;

#define GPTR(p) (const __attribute__((address_space(1))) unsigned int*)(p)
#define LPTR(p) (__attribute__((address_space(3))) unsigned int*)(p)

static __device__ __forceinline__ float bf2f(unsigned int u16) {
    unsigned int x = u16 << 16;
    float f;
    __builtin_memcpy(&f, &x, 4);
    return f;
}
static __device__ __forceinline__ float bitsf(unsigned int x) {
    float f;
    __builtin_memcpy(&f, &x, 4);
    return f;
}
static __device__ __forceinline__ unsigned short f2bf(float f) {
    unsigned int x;
    __builtin_memcpy(&x, &f, 4);
    unsigned int r = x + 0x7fffu + ((x >> 16) & 1u);   // RNE
    return (unsigned short)(r >> 16);
}
static __device__ __forceinline__ float fexp2(float x) {
#if __has_builtin(__builtin_amdgcn_exp2f)
    return __builtin_amdgcn_exp2f(x);
#else
    return exp2f(x);
#endif
}

// packed f32 (CDNA3/4 VOP3P): 2 f32 per instruction
static __device__ __forceinline__ float2 pk_fma(float2 a, float2 b, float2 c) {
    float2 d;
    asm("v_pk_fma_f32 %0, %1, %2, %3" : "=v"(d) : "v"(a), "v"(b), "v"(c));
    return d;
}
static __device__ __forceinline__ float2 pk_add(float2 a, float2 b) {
    float2 d;
    asm("v_pk_add_f32 %0, %1, %2" : "=v"(d) : "v"(a), "v"(b));
    return d;
}
static __device__ __forceinline__ float2 pk_mul(float2 a, float2 b) {
    float2 d;
    asm("v_pk_mul_f32 %0, %1, %2" : "=v"(d) : "v"(a), "v"(b));
    return d;
}

// ---------------- f32 -> bf16 bulk convert (8 elems/thread) ----------------
__global__ __launch_bounds__(256)
void cvt_bf16(const float* __restrict__ in, unsigned short* __restrict__ out, int n8) {
    int i = blockIdx.x * 256 + threadIdx.x;
    if (i >= n8) return;
    const float4* p = (const float4*)in + (size_t)i * 2;
    float4 u0 = p[0], u1 = p[1];
    bfrag pk;
    pk[0] = (short)f2bf(u0.x); pk[1] = (short)f2bf(u0.y);
    pk[2] = (short)f2bf(u0.z); pk[3] = (short)f2bf(u0.w);
    pk[4] = (short)f2bf(u1.x); pk[5] = (short)f2bf(u1.y);
    pk[6] = (short)f2bf(u1.z); pk[7] = (short)f2bf(u1.w);
    *(bfrag*)(out + (size_t)i * 8) = pk;
}

// ---------------- CSR build ----------------
__global__ void zero_int(int* p, int n) {
    int i = blockIdx.x * blockDim.x + threadIdx.x;
    if (i < n) p[i] = 0;
}

__global__ void count_kernel(const int* __restrict__ dstRow, int* __restrict__ cnt) {
    int e = blockIdx.x * blockDim.x + threadIdx.x;
    if (e >= ETOT) return;
    int d = (e < NEDGE) ? dstRow[e] : (e - NEDGE);
    atomicAdd(&cnt[d], 1);
}

// two-level parallel scan
__global__ __launch_bounds__(256)
void scan_blk(const int* __restrict__ cnt, int* __restrict__ off, int* __restrict__ blkTot) {
    __shared__ int buf[256];
    const int t = threadIdx.x;
    const int i = blockIdx.x * 256 + t;
    int v = (i < NODES) ? cnt[i] : 0;
    buf[t] = v;
    __syncthreads();
    #pragma unroll
    for (int d = 1; d < 256; d <<= 1) {
        int add = (t >= d) ? buf[t - d] : 0;
        __syncthreads();
        buf[t] += add;
        __syncthreads();
    }
    if (i < NODES) off[i] = buf[t] - v;   // local exclusive
    if (t == 255) blkTot[blockIdx.x] = buf[255];
}

__global__ __launch_bounds__(256)
void scan_top(const int* __restrict__ blkTot, int* __restrict__ blkOff, int* __restrict__ offEnd) {
    __shared__ int buf[256];
    const int t = threadIdx.x;
    int v = (t < SCAN_NB) ? blkTot[t] : 0;
    buf[t] = v;
    __syncthreads();
    #pragma unroll
    for (int d = 1; d < 256; d <<= 1) {
        int add = (t >= d) ? buf[t - d] : 0;
        __syncthreads();
        buf[t] += add;
        __syncthreads();
    }
    if (t < SCAN_NB) blkOff[t] = buf[t] - v;
    if (t == 255) *offEnd = buf[255];
}

__global__ __launch_bounds__(256)
void scan_fix(int* __restrict__ off, int* __restrict__ wrk, const int* __restrict__ blkOff) {
    const int i = blockIdx.x * 256 + threadIdx.x;
    if (i < NODES) {
        int v = off[i] + blkOff[blockIdx.x];
        off[i] = v;
        wrk[i] = v;
    }
}

// store SOURCE NODE directly in csr (kills one dependent load in the fused kernels)
__global__ void place_kernel(const int* __restrict__ srcRow, const int* __restrict__ dstRow,
                             int* __restrict__ wrk, int* __restrict__ csr) {
    int e = blockIdx.x * blockDim.x + threadIdx.x;
    if (e >= ETOT) return;
    int d, s;
    if (e < NEDGE) { d = dstRow[e]; s = srcRow[e]; }
    else           { d = e - NEDGE; s = d; }
    int slot = atomicAdd(&wrk[d], 1);
    csr[slot] = s;
}

// ---------------- weight transpose+cast: Wt[n][k] = bf16(W[k][n]) ----------------
__global__ void prep_w(const float* __restrict__ Wl, const float* __restrict__ Wr,
                       unsigned short* __restrict__ Wt, int K, int Nhalf) {
    int idx = blockIdx.x * 256 + threadIdx.x;   // n*K + k
    int n = idx / K;
    int k = idx - n * K;
    if (n >= 2 * Nhalf) return;
    float v = (n < Nhalf) ? Wl[(size_t)k * Nhalf + n] : Wr[(size_t)k * Nhalf + (n - Nhalf)];
    Wt[idx] = f2bf(v);
}

// ---------------- MFMA dual GEMM: double-buffered LDS + counted vmcnt + XCD swizzle ----------------
#define GBM 128
#define GBN 128
#define GBK 32

template<typename OUTT, bool SWZ>
__global__ __launch_bounds__(256)
void mfma_gemm(const unsigned short* __restrict__ Ab, const unsigned short* __restrict__ Bt,
               const float* __restrict__ bl, const float* __restrict__ br,
               OUTT* __restrict__ Cl, OUTT* __restrict__ Cr,
               int M, int K, int Nrows, int Nhalf, int nbnShift)
{
    __shared__ __align__(16) unsigned short As[2][GBM * GBK];
    __shared__ __align__(16) unsigned short Bs[2][GBN * GBK];

    const int tid  = threadIdx.x;
    const int lane = tid & 63;
    const int w    = tid >> 6;
    const int wr   = w >> 1;
    const int wc   = w & 1;

    // bijective XCD-chunk swizzle (m204): same-A-panel tiles land on the same XCD L2
    int tile;
    if constexpr (SWZ) {
        const int nwg = gridDim.x;
        const int q = nwg >> 3, r = nwg & 7;
        const int xcd = blockIdx.x & 7;
        const int idx = blockIdx.x >> 3;
        tile = (xcd < r ? xcd * (q + 1) : r * (q + 1) + (xcd - r) * q) + idx;
    } else {
        tile = blockIdx.x;
    }
    const int bx   = tile >> nbnShift;
    const int by   = tile & ((1 << nbnShift) - 1);
    const int row0 = bx * GBM;
    const int col0 = by * GBN;

    facc acc[4][4];
    #pragma unroll
    for (int i = 0; i < 4; ++i)
        #pragma unroll
        for (int j = 0; j < 4; ++j) {
            facc z = {0.f, 0.f, 0.f, 0.f};
            acc[i][j] = z;
        }

    const int rA  = lane >> 2;            // row within 16-row chunk
    const int kgA = (lane & 3) ^ ((rA >> 1) & 3);   // pre-swizzled source k-group

    // 4 unconditional global_load_lds per wave per stage (row-clamped so the
    // vmcnt count is wave-uniform; garbage rows are discarded at the C-write)
    #define STAGE(bufi, k0)                                                     \
    {                                                                           \
        _Pragma("unroll")                                                       \
        for (int p = 0; p < 2; ++p) {                                           \
            const int chunk = p * 4 + w;                                        \
            const int r_loc = chunk * 16 + rA;                                  \
            const int ga = min(row0 + r_loc, M - 1);                            \
            __builtin_amdgcn_global_load_lds(                                   \
                GPTR(Ab + (size_t)ga * K + (k0) + kgA * 8),                     \
                LPTR(&As[bufi][chunk * 512]), 16, 0, 0);                        \
            const int gb = min(col0 + r_loc, Nrows - 1);                        \
            __builtin_amdgcn_global_load_lds(                                   \
                GPTR(Bt + (size_t)gb * K + (k0) + kgA * 8),                     \
                LPTR(&Bs[bufi][chunk * 512]), 16, 0, 0);                        \
        }                                                                       \
    }

    const int fr    = lane & 15;
    const int sRead = (lane >> 4) ^ ((fr >> 1) & 3);
    const int nt    = K / GBK;

    STAGE(0, 0);
    for (int t = 0; t < nt; ++t) {
        const int cur = t & 1;
        if (t + 1 < nt) {
            STAGE(cur ^ 1, (t + 1) * GBK);
            asm volatile("s_waitcnt vmcnt(4)" ::: "memory");
        } else {
            asm volatile("s_waitcnt vmcnt(0)" ::: "memory");
        }
        __builtin_amdgcn_s_barrier();
        __builtin_amdgcn_sched_barrier(0);

        bfrag af[4], bfv[4];
        #pragma unroll
        for (int mi = 0; mi < 4; ++mi)
            af[mi] = *(const bfrag*)(&As[cur][(wr * 64 + mi * 16 + fr) * 32 + sRead * 8]);
        #pragma unroll
        for (int ni = 0; ni < 4; ++ni)
            bfv[ni] = *(const bfrag*)(&Bs[cur][(wc * 64 + ni * 16 + fr) * 32 + sRead * 8]);
        #pragma unroll
        for (int mi = 0; mi < 4; ++mi)
            #pragma unroll
            for (int ni = 0; ni < 4; ++ni)
                acc[mi][ni] = __builtin_amdgcn_mfma_f32_16x16x32_bf16(
                    af[mi], bfv[ni], acc[mi][ni], 0, 0, 0);

        __builtin_amdgcn_s_barrier();
    }
    #undef STAGE

    #pragma unroll
    for (int mi = 0; mi < 4; ++mi) {
        const int rbase = row0 + wr * 64 + mi * 16 + ((lane >> 4) << 2);
        #pragma unroll
        for (int ni = 0; ni < 4; ++ni) {
            const int col = col0 + wc * 64 + ni * 16 + (lane & 15);
            #pragma unroll
            for (int rg = 0; rg < 4; ++rg) {
                int r = rbase + rg;
                if (r >= M) continue;
                float v = acc[mi][ni][rg];
                if (col < Nhalf) {
                    v += bl[col];
                    if constexpr (sizeof(OUTT) == 2)
                        Cl[(size_t)r * Nhalf + col] = (OUTT)f2bf(v);
                    else
                        Cl[(size_t)r * Nhalf + col] = (OUTT)v;
                } else if (col < 2 * Nhalf) {
                    int c2 = col - Nhalf;
                    v += br[c2];
                    if constexpr (sizeof(OUTT) == 2)
                        Cr[(size_t)r * Nhalf + c2] = (OUTT)f2bf(v);
                    else
                        Cr[(size_t)r * Nhalf + c2] = (OUTT)v;
                }
            }
        }
    }
}

// ---------------- fused layer 1: one WAVE per node, exp2 + defer-max + pk f32 ----------------
__global__ __launch_bounds__(256)
void fused_l1(const int* __restrict__ off,
              const int* __restrict__ csr, const unsigned short* __restrict__ xl,
              const unsigned short* xr, const float* __restrict__ att,
              const float* __restrict__ bias, unsigned short* hout)
{
    const int lane = threadIdx.x & 63;
    const int n    = blockIdx.x * 4 + (threadIdx.x >> 6);
    if (n >= NODES) return;

    const int a = off[n], b = off[n + 1];

    const uint2 xrn = *(const uint2*)(xr + (size_t)n * C1 + lane * 4);
    const float2 xr01 = {bitsf(xrn.x << 16), bitsf(xrn.x & 0xffff0000u)};
    const float2 xr23 = {bitsf(xrn.y << 16), bitsf(xrn.y & 0xffff0000u)};
    const float4 wv = *(const float4*)(att + lane * 4);
    const float L2E = 1.4426950408889634f;
    const float2 w6_01 = {wv.x * (0.6f * L2E), wv.y * (0.6f * L2E)};
    const float2 w4_01 = {wv.x * (0.4f * L2E), wv.y * (0.4f * L2E)};
    const float2 w6_23 = {wv.z * (0.6f * L2E), wv.w * (0.6f * L2E)};
    const float2 w4_23 = {wv.z * (0.4f * L2E), wv.w * (0.4f * L2E)};

    float m = -INFINITY, d = 0.f;
    float2 ac01 = {0.f, 0.f}, ac23 = {0.f, 0.f};

    for (int base = a; base < b; base += 64) {
        const int cn = min(64, b - base);
        int mySrc = 0;
        if (lane < cn) mySrc = csr[base + lane];   // src stored directly

        #define ROW1(i) (*(const uint2*)(xl + (size_t)__shfl(mySrc, min((i), cn - 1)) * C1 + lane * 4))
        #define PROC1(i, R)                                                          \
        {                                                                            \
            const float2 x01 = {bitsf((R).x << 16), bitsf((R).x & 0xffff0000u)};     \
            const float2 x23 = {bitsf((R).y << 16), bitsf((R).y & 0xffff0000u)};     \
            const float2 v01 = pk_add(x01, xr01);                                    \
            const float2 v23 = pk_add(x23, xr23);                                    \
            const float2 av01 = {fabsf(v01.x), fabsf(v01.y)};                        \
            const float2 av23 = {fabsf(v23.x), fabsf(v23.y)};                        \
            float2 p2 = pk_mul(w6_01, v01);                                          \
            p2 = pk_fma(w4_01, av01, p2);                                            \
            p2 = pk_fma(w6_23, v23, p2);                                             \
            p2 = pk_fma(w4_23, av23, p2);                                            \
            float p = p2.x + p2.y;                                                   \
            p += __shfl_xor(p, 1);                                                   \
            p += __shfl_xor(p, 2);                                                   \
            p += __shfl_xor(p, 4);                                                   \
            if (__any(p > m + 8.f)) {                                                \
                const float mN = fmaxf(m, p);                                        \
                const float sc = fexp2(m - mN);                                      \
                const float wg = fexp2(p - mN);                                      \
                m = mN;                                                              \
                d = d * sc + wg;                                                     \
                const float2 s2 = {sc, sc};                                          \
                const float2 g2 = {wg, wg};                                          \
                ac01 = pk_fma(g2, x01, pk_mul(ac01, s2));                            \
                ac23 = pk_fma(g2, x23, pk_mul(ac23, s2));                            \
            } else {                                                                 \
                const float wg = fexp2(p - m);                                       \
                d += wg;                                                             \
                const float2 g2 = {wg, wg};                                          \
                ac01 = pk_fma(g2, x01, ac01);                                        \
                ac23 = pk_fma(g2, x23, ac23);                                        \
            }                                                                        \
        }

        uint2 r0, r1, r2, r3;
        r0 = ROW1(0);
        if (1 < cn) r1 = ROW1(1);
        if (2 < cn) r2 = ROW1(2);
        if (3 < cn) r3 = ROW1(3);
        for (int i = 0; i < cn; i += 4) {
            PROC1(i, r0);
            if (i + 4 < cn) r0 = ROW1(i + 4);
            if (i + 1 < cn) {
                PROC1(i + 1, r1);
                if (i + 5 < cn) r1 = ROW1(i + 5);
            }
            if (i + 2 < cn) {
                PROC1(i + 2, r2);
                if (i + 6 < cn) r2 = ROW1(i + 6);
            }
            if (i + 3 < cn) {
                PROC1(i + 3, r3);
                if (i + 7 < cn) r3 = ROW1(i + 7);
            }
        }
        #undef ROW1
        #undef PROC1
    }

    const float inv = 1.f / d;
    const float4 bv = *(const float4*)(bias + lane * 4);
    float v0 = ac01.x * inv + bv.x, v1 = ac01.y * inv + bv.y;
    float v2 = ac23.x * inv + bv.z, v3 = ac23.y * inv + bv.w;
    v0 = v0 > 0.f ? v0 : (expf(v0) - 1.f);
    v1 = v1 > 0.f ? v1 : (expf(v1) - 1.f);
    v2 = v2 > 0.f ? v2 : (expf(v2) - 1.f);
    v3 = v3 > 0.f ? v3 : (expf(v3) - 1.f);
    uint2 o;
    o.x = (unsigned int)f2bf(v0) | ((unsigned int)f2bf(v1) << 16);
    o.y = (unsigned int)f2bf(v2) | ((unsigned int)f2bf(v3) << 16);
    *(uint2*)(hout + (size_t)n * C1 + lane * 4) = o;
}

// ---------------- fused layer 2: 8-edge-parallel groups + log_softmax ----------------
__global__ __launch_bounds__(256)
void fused_l2(const int* __restrict__ off,
              const int* __restrict__ csr, const float* __restrict__ h2l,
              const float* __restrict__ h2r, const float* __restrict__ att,
              const float* __restrict__ bias, float* __restrict__ out)
{
    const int lane = threadIdx.x & 63;
    const int n    = blockIdx.x * 4 + (threadIdx.x >> 6);
    if (n >= NODES) return;
    const int l8 = lane & 7;    // channel sub-index
    const int g  = lane >> 3;   // edge group

    const int a = off[n], b = off[n + 1];
    const float L2E = 1.4426950408889634f;

    float w6[5], w4[5], xr[5];
    #pragma unroll
    for (int j = 0; j < 5; ++j) {
        const int c = l8 + 8 * j;
        const float w = att[c];
        w6[j] = w * (0.6f * L2E);
        w4[j] = w * (0.4f * L2E);
        xr[j] = h2r[(size_t)n * C2 + c];
    }

    float m = -INFINITY, dl = 0.f;
    float acc[5] = {0.f, 0.f, 0.f, 0.f, 0.f};

    for (int base = a; base < b; base += 64) {
        const int cn = min(64, b - base);
        int mySrc = 0;
        if (lane < cn) mySrc = csr[base + lane];   // src stored directly

        for (int c0 = 0; c0 < cn; c0 += 8) {
            const int idx = c0 + g;
            const bool active = idx < cn;
            const int src = __shfl(mySrc, min(idx, cn - 1));
            const float* row = h2l + (size_t)src * C2 + l8;
            float R[5];
            #pragma unroll
            for (int j = 0; j < 5; ++j) R[j] = row[8 * j];

            float p = 0.f;
            #pragma unroll
            for (int j = 0; j < 5; ++j) {
                const float v = R[j] + xr[j];
                p = fmaf(w6[j], v, p);
                p = fmaf(w4[j], fabsf(v), p);
            }
            p += __shfl_xor(p, 1);
            p += __shfl_xor(p, 2);
            p += __shfl_xor(p, 4);
            if (!active) p = -INFINITY;

            if (__any(p > m + 8.f)) {
                float pm = p;
                pm = fmaxf(pm, __shfl_xor(pm, 8));
                pm = fmaxf(pm, __shfl_xor(pm, 16));
                pm = fmaxf(pm, __shfl_xor(pm, 32));
                const float mN = fmaxf(m, pm);
                const float sc = fexp2(m - mN);
                const float wg = fexp2(p - mN);
                m = mN;
                dl = dl * sc + wg;
                #pragma unroll
                for (int j = 0; j < 5; ++j) acc[j] = fmaf(wg, R[j], acc[j] * sc);
            } else {
                const float wg = fexp2(p - m);
                dl += wg;
                #pragma unroll
                for (int j = 0; j < 5; ++j) acc[j] = fmaf(wg, R[j], acc[j]);
            }
        }
    }

    // cross-group butterfly reductions (d and acc)
    #pragma unroll
    for (int o = 8; o < 64; o <<= 1) {
        dl += __shfl_xor(dl, o);
        #pragma unroll
        for (int j = 0; j < 5; ++j) acc[j] += __shfl_xor(acc[j], o);
    }

    const float inv = 1.f / dl;
    float v[5];
    float mx = -INFINITY;
    #pragma unroll
    for (int j = 0; j < 5; ++j) {
        v[j] = acc[j] * inv + bias[l8 + 8 * j];
        mx = fmaxf(mx, v[j]);
    }
    mx = fmaxf(mx, __shfl_xor(mx, 1));
    mx = fmaxf(mx, __shfl_xor(mx, 2));
    mx = fmaxf(mx, __shfl_xor(mx, 4));
    float s = 0.f;
    #pragma unroll
    for (int j = 0; j < 5; ++j) s += expf(v[j] - mx);
    s += __shfl_xor(s, 1);
    s += __shfl_xor(s, 2);
    s += __shfl_xor(s, 4);
    const float lg = logf(s);
    if (g == 0) {
        #pragma unroll
        for (int j = 0; j < 5; ++j)
            out[(size_t)n * C2 + l8 + 8 * j] = v[j] - mx - lg;
    }
}

extern "C" void kernel_launch(void* const* d_in, const int* in_sizes, int n_in,
                              void* d_out, int out_size, void* d_ws, size_t ws_size,
                              hipStream_t stream)
{
    const float* x     = (const float*)d_in[0];
    const int*   ei    = (const int*)  d_in[1];
    const float* W1l   = (const float*)d_in[2];
    const float* b1l   = (const float*)d_in[3];
    const float* W1r   = (const float*)d_in[4];
    const float* b1r   = (const float*)d_in[5];
    const float* att1  = (const float*)d_in[6];
    const float* bias1 = (const float*)d_in[7];
    const float* W2l   = (const float*)d_in[8];
    const float* b2l   = (const float*)d_in[9];
    const float* W2r   = (const float*)d_in[10];
    const float* b2r   = (const float*)d_in[11];
    const float* att2  = (const float*)d_in[12];
    const float* bias2 = (const float*)d_in[13];
    float* out = (float*)d_out;

    float* ws = (float*)d_ws;
    unsigned short* xl1 = (unsigned short*)ws;               // 12.8M bf16 (25.6 MB)
    unsigned short* xr1 = (unsigned short*)(ws + 6400000);   // 12.8M bf16 (doubles as h)
    unsigned short* xb  = (unsigned short*)(ws + 12800000);  // x in bf16, 12.8M bf16
    int*   csr    = (int*)(ws + 19200000);                   // 450K
    int*   off    = csr + ETOT;                              // 50001
    int*   cnt    = off + (NODES + 1);
    int*   wrk    = cnt + NODES;
    int*   blkTot = wrk + NODES;
    int*   blkOff = blkTot + SCAN_NB;
    unsigned short* Wt1 = (unsigned short*)(ws + 19810000);  // 512*256 bf16
    unsigned short* Wt2 = (unsigned short*)(ws + 19880000);  // 80*256 bf16
    unsigned short* h = xr1;                                 // layer-1 output (in place)
    float* h2l = ws;                                         // 2M f32 (over dead xl1)
    float* h2r = ws + 2000000;

    const int* srcRow = ei;
    const int* dstRow = ei + NEDGE;

    // ---- CSR build + input/weight prep ----
    zero_int<<<(NODES + 255) / 256, 256, 0, stream>>>(cnt, NODES);
    count_kernel<<<(ETOT + 255) / 256, 256, 0, stream>>>(dstRow, cnt);
    scan_blk<<<SCAN_NB, 256, 0, stream>>>(cnt, off, blkTot);
    scan_top<<<1, 256, 0, stream>>>(blkTot, blkOff, off + NODES);
    scan_fix<<<SCAN_NB, 256, 0, stream>>>(off, wrk, blkOff);
    place_kernel<<<(ETOT + 255) / 256, 256, 0, stream>>>(srcRow, dstRow, wrk, csr);

    cvt_bf16<<<(NODES * DIN / 8 + 255) / 256, 256, 0, stream>>>(x, xb, NODES * DIN / 8);
    prep_w<<<(512 * 256 + 255) / 256, 256, 0, stream>>>(W1l, W1r, Wt1, DIN, C1);
    prep_w<<<(80 * 256 + 255) / 256, 256, 0, stream>>>(W2l, W2r, Wt2, C1, C2);

    // ---- layer 1 ----
    mfma_gemm<unsigned short, true><<<((NODES + GBM - 1) / GBM) * 4, 256, 0, stream>>>(
        xb, Wt1, b1l, b1r, xl1, xr1, NODES, DIN, 2 * C1, C1, 2);
    fused_l1<<<(NODES + 3) / 4, 256, 0, stream>>>(off, csr, xl1, xr1, att1, bias1, h);

    // ---- layer 2 ----
    mfma_gemm<float, false><<<(NODES + GBM - 1) / GBM, 256, 0, stream>>>(
        h, Wt2, b2l, b2r, h2l, h2r, NODES, C1, 2 * C2, C2, 0);
    fused_l2<<<(NODES + 3) / 4, 256, 0, stream>>>(off, csr, h2l, h2r, att2, bias2, out);
}